// Round 12
// baseline (1806.228 us; speedup 1.0000x reference)
//
#include <hip/hip_runtime.h>
#include <stdint.h>

typedef unsigned short u16;
typedef unsigned int u32;
typedef __attribute__((ext_vector_type(4))) float f32x4;
typedef __attribute__((ext_vector_type(8))) __bf16 bf16x8;
typedef __attribute__((ext_vector_type(4))) unsigned short u16x4;

#define DEVINL __device__ __forceinline__

// ---------- bf16 helpers (manual RTNE; storage is u16) ----------
DEVINL u16 f2bf(float f) {
  u32 u = __builtin_bit_cast(u32, f);
  u32 r = (u + 0x7fffu + ((u >> 16) & 1u)) >> 16;
  return (u16)r;
}
DEVINL float bf2f(u16 h) {
  u32 u = ((u32)h) << 16;
  return __builtin_bit_cast(float, u);
}

DEVINL f32x4 mfma16(bf16x8 a, bf16x8 b, f32x4 c) {
  return __builtin_amdgcn_mfma_f32_16x16x32_bf16(a, b, c, 0, 0, 0);
}

// ---------- async global->LDS 16B ----------
DEVINL void gload_lds16(const void* g, void* l) {
  auto gp = (__attribute__((address_space(1))) void*)(reinterpret_cast<uintptr_t>(g));
  auto lp = (__attribute__((address_space(3))) void*)(u32)(reinterpret_cast<uintptr_t>(l));
  __builtin_amdgcn_global_load_lds(gp, lp, 16, 0, 0);
}

// Stage a [ROWS][KCS*8] bf16 k-contiguous tile. LDS linear; global SOURCE slot
// inverse-XOR-swizzled so swizzled reads are conflict-free.
template <int ROWS, int KCS, int NT>
DEVINL void stage_tile(const u16* __restrict__ g, int ld, char* lds, int tid) {
  constexpr int SWZ = (KCS - 1) < 7 ? (KCS - 1) : 7;
  constexpr int CH = ROWS * KCS;  // 16B chunks
#pragma unroll
  for (int c0 = 0; c0 < CH; c0 += NT) {
    int c = c0 + tid;
    int row = c / KCS;
    int slot = c & (KCS - 1);
    const u16* src = g + (size_t)row * ld + ((slot ^ (row & SWZ)) << 3);
    char* dst = lds + (((size_t)(c0 + (tid & ~63))) << 4);  // wave-uniform base
    gload_lds16(src, dst);
  }
}

// Fragment read: 8 bf16 along k at given row. kslot in [0, KCS).
template <int KCS, int SWZM>
DEVINL bf16x8 fragk(const char* lds, int row, int kslot) {
  return *reinterpret_cast<const bf16x8*>(
      lds + (size_t)row * (KCS * 16) + (size_t)((kslot ^ (row & SWZM)) << 4));
}

// ============================ GroupNorm =====================================
__global__ __launch_bounds__(256) void gn_stats(const float* __restrict__ x,
                                                float* __restrict__ smean,
                                                float* __restrict__ srstd) {
  const int bg = blockIdx.x;
  const float4* base = reinterpret_cast<const float4*>(x + (size_t)bg * 65536);
  float s = 0.f, ss = 0.f;
  for (int i = threadIdx.x; i < 16384; i += 256) {
    float4 v = base[i];
    s += v.x + v.y + v.z + v.w;
    ss += v.x * v.x + v.y * v.y + v.z * v.z + v.w * v.w;
  }
#pragma unroll
  for (int off = 1; off < 64; off <<= 1) {
    s += __shfl_xor(s, off);
    ss += __shfl_xor(ss, off);
  }
  __shared__ float rs_[4], rss_[4];
  int w = threadIdx.x >> 6;
  if ((threadIdx.x & 63) == 0) { rs_[w] = s; rss_[w] = ss; }
  __syncthreads();
  if (threadIdx.x == 0) {
    float S = rs_[0] + rs_[1] + rs_[2] + rs_[3];
    float SS = rss_[0] + rss_[1] + rss_[2] + rss_[3];
    float mu = S * (1.0f / 65536.0f);
    float var = SS * (1.0f / 65536.0f) - mu * mu;
    smean[bg] = mu;
    srstd[bg] = 1.0f / sqrtf(var + 1e-5f);
  }
}

__global__ __launch_bounds__(256) void gn_apply(
    const float* __restrict__ x, const float* __restrict__ gamma,
    const float* __restrict__ beta, const float* __restrict__ smean,
    const float* __restrict__ srstd, u16* __restrict__ hhi, u16* __restrict__ hlo) {
  __shared__ __align__(16) u16 thi[128][136];
  __shared__ __align__(16) u16 tlo[128][136];
  const int b = blockIdx.z, p0 = blockIdx.y * 128, c0 = blockIdx.x * 128;
  const int tid = threadIdx.x;
  const int ci = tid >> 1, ph = tid & 1;
  const int c = c0 + ci;
  const int bg = b * 32 + (c >> 4);
  const float mu = smean[bg], rstd = srstd[bg];
  const float ga = gamma[c] * rstd;
  const float be = beta[c] - mu * ga;
  const float* xrow = x + ((size_t)(b * 512 + c)) * 4096 + p0;
#pragma unroll
  for (int s = 0; s < 16; s++) {
    int pj = ph * 4 + s * 8;
    float4 v = *reinterpret_cast<const float4*>(xrow + pj);
    float h0 = v.x * ga + be, h1 = v.y * ga + be, h2 = v.z * ga + be, h3 = v.w * ga + be;
    u16 a0 = f2bf(h0), a1 = f2bf(h1), a2 = f2bf(h2), a3 = f2bf(h3);
    thi[pj + 0][ci] = a0; tlo[pj + 0][ci] = f2bf(h0 - bf2f(a0));
    thi[pj + 1][ci] = a1; tlo[pj + 1][ci] = f2bf(h1 - bf2f(a1));
    thi[pj + 2][ci] = a2; tlo[pj + 2][ci] = f2bf(h2 - bf2f(a2));
    thi[pj + 3][ci] = a3; tlo[pj + 3][ci] = f2bf(h3 - bf2f(a3));
  }
  __syncthreads();
  u16* oh = hhi + ((size_t)b * 4096 + p0) * 512 + c0;
  u16* ol = hlo + ((size_t)b * 4096 + p0) * 512 + c0;
  for (int cc = tid; cc < 2048; cc += 256) {
    int p = cc >> 4, sli = cc & 15;
    *reinterpret_cast<bf16x8*>(oh + (size_t)p * 512 + sli * 8) =
        *reinterpret_cast<const bf16x8*>(&thi[p][sli * 8]);
    *reinterpret_cast<bf16x8*>(ol + (size_t)p * 512 + sli * 8) =
        *reinterpret_cast<const bf16x8*>(&tlo[p][sli * 8]);
  }
}

// ============================ weight prep ===================================
__global__ __launch_bounds__(256) void prep_w(
    const float* __restrict__ wq, const float* __restrict__ wk,
    const float* __restrict__ wv, const float* __restrict__ wo,
    u16* __restrict__ wqh, u16* __restrict__ wql, u16* __restrict__ wkh,
    u16* __restrict__ wkl, u16* __restrict__ wvb, u16* __restrict__ wob) {
  int i = blockIdx.x * 256 + threadIdx.x;
  if (i >= 262144) return;
  float a = wq[i]; u16 h = f2bf(a); wqh[i] = h; wql[i] = f2bf(a - bf2f(h));
  float bb = wk[i]; h = f2bf(bb); wkh[i] = h; wkl[i] = f2bf(bb - bf2f(h));
  wvb[i] = f2bf(wv[i]);
  wob[i] = f2bf(wo[i]);
}

// ============================ conv GEMM =====================================
template <int MODE>
__global__ __launch_bounds__(256, 2) void conv_gemm(
    const u16* __restrict__ A0, const u16* __restrict__ A1,
    const u16* __restrict__ B0, const u16* __restrict__ B1,
    const float* __restrict__ bias, const float* __restrict__ xres,
    u16* __restrict__ o0, u16* __restrict__ o1, float* __restrict__ of,
    long sAb, long sBb) {
  constexpr int LDSZ = (MODE == 0) ? 65536 : ((MODE == 1) ? 34816 : 32768);
  __shared__ __align__(16) char lds[LDSZ];
  char* ldsA = lds;
  char* ldsB = lds + 16384;

  const int b = blockIdx.z;
  const int n0 = blockIdx.x * 128;
  const int m0 = blockIdx.y * 128;
  const int tid = threadIdx.x;
  const int lane = tid & 63;
  const int w = tid >> 6;
  const int li = lane & 15, gq = lane >> 4;
  const int wm = (w >> 1) * 64, wn = (w & 1) * 64;

  const u16* Ag = A0 + (size_t)b * sAb + (size_t)m0 * 512;
  const u16* Bg = B0 + (size_t)b * sBb + (size_t)n0 * 512;
  const u16* Ag1 = (MODE == 0) ? (A1 + (size_t)b * sAb + (size_t)m0 * 512) : nullptr;
  const u16* Bg1 = (MODE == 0) ? (B1 + (size_t)b * sBb + (size_t)n0 * 512) : nullptr;

  f32x4 acc[4][4] = {};

  for (int k0 = 0; k0 < 512; k0 += 64) {
    __syncthreads();
    stage_tile<128, 8, 256>(Ag + k0, 512, ldsA, tid);
    stage_tile<128, 8, 256>(Bg + k0, 512, ldsB, tid);
    if (MODE == 0) {
      stage_tile<128, 8, 256>(Ag1 + k0, 512, lds + 32768, tid);
      stage_tile<128, 8, 256>(Bg1 + k0, 512, lds + 49152, tid);
    }
    __syncthreads();
#pragma unroll
    for (int kk = 0; kk < 2; kk++) {
      bf16x8 aF[4], bF[4], aL[4], bL[4];
#pragma unroll
      for (int t = 0; t < 4; t++) {
        aF[t] = fragk<8, 7>(ldsA, wm + t * 16 + li, kk * 4 + gq);
        bF[t] = fragk<8, 7>(ldsB, wn + t * 16 + li, kk * 4 + gq);
        if (MODE == 0) {
          aL[t] = fragk<8, 7>(lds + 32768, wm + t * 16 + li, kk * 4 + gq);
          bL[t] = fragk<8, 7>(lds + 49152, wn + t * 16 + li, kk * 4 + gq);
        }
      }
#pragma unroll
      for (int mt = 0; mt < 4; mt++)
#pragma unroll
        for (int nt = 0; nt < 4; nt++) {
          acc[mt][nt] = mfma16(aF[mt], bF[nt], acc[mt][nt]);
          if (MODE == 0) {
            acc[mt][nt] = mfma16(aF[mt], bL[nt], acc[mt][nt]);
            acc[mt][nt] = mfma16(aL[mt], bF[nt], acc[mt][nt]);
          }
        }
    }
  }

  if (MODE == 0) {
#pragma unroll
    for (int nt = 0; nt < 4; nt++) {
      int gn = n0 + wn + nt * 16 + li;
      float bs = bias[gn];
#pragma unroll
      for (int mt = 0; mt < 4; mt++)
#pragma unroll
        for (int r = 0; r < 4; r++) {
          int gm = m0 + wm + mt * 16 + gq * 4 + r;
          float v = acc[mt][nt][r] + bs;
          u16 hi = f2bf(v);
          size_t idx = ((size_t)b * 4096 + gm) * 512 + gn;
          o0[idx] = hi;
          o1[idx] = f2bf(v - bf2f(hi));
        }
    }
  } else if (MODE == 1) {
    __syncthreads();
    u16* vt = (u16*)lds;  // [128 n][136 m]
#pragma unroll
    for (int nt = 0; nt < 4; nt++) {
      int ol = wn + nt * 16 + li;
      float bs = bias[n0 + ol];
#pragma unroll
      for (int mt = 0; mt < 4; mt++)
#pragma unroll
        for (int r = 0; r < 4; r++) {
          int pl = wm + mt * 16 + gq * 4 + r;
          vt[ol * 136 + pl] = f2bf(acc[mt][nt][r] + bs);
        }
    }
    __syncthreads();
    for (int c = tid; c < 2048; c += 256) {
      int o = c >> 4, sl = c & 15;
      bf16x8 val = *reinterpret_cast<const bf16x8*>(vt + o * 136 + sl * 8);
      *reinterpret_cast<bf16x8*>(o0 + ((size_t)b * 512 + n0 + o) * 4096 + m0 + sl * 8) = val;
    }
  } else {
#pragma unroll
    for (int nt = 0; nt < 4; nt++) {
      int gn = n0 + wn + nt * 16 + li;
#pragma unroll
      for (int mt = 0; mt < 4; mt++)
#pragma unroll
        for (int r = 0; r < 4; r++) {
          int gm = m0 + wm + mt * 16 + gq * 4 + r;
          size_t idx = ((size_t)b * 512 + gm) * 4096 + gn;
          of[idx] = acc[mt][nt][r] + bias[gm] + xres[idx];
        }
    }
  }
}

// ============================ flash attention ===============================
// R8 structure FUSED x2: 1024 threads = 16 waves = 2 groups of 8; group g owns
// q-rows [i0+64g, i0+64g+64). K hi/lo staged ONCE per block (shared by both
// groups). Grid 256 = 1 block/CU, SINGLE generation (no staggered K sweeps).
// __launch_bounds__(1024,1) -> 256-reg budget (measured mapping 256/arg) ->
// no spills at ~190 live; 4 waves/SIMD resident (16x~190=3040 <= 2048*4 pool)
// -> 2x latency hiding vs all prior rounds (stuck at 2 waves/SIMD).
// Per group: swapped QK mfma, in-lane softmax (R8), packed 8B P writes.
// P group0 -> buf1.Khi [32K:48K), P group1 -> buf1.Klo [48K:64K) (dead after
// chunk7 compute, proven by B1 barrier).
#define S2C 32.64446259f  // sqrt(512)*log2(e)

__global__ __launch_bounds__(1024, 1) void flash_attn(
    const u16* __restrict__ qhi, const u16* __restrict__ qlo,
    const u16* __restrict__ khi, const u16* __restrict__ klo,
    const u16* __restrict__ vbuf, u16* __restrict__ oout) {
  __shared__ __align__(16) char ldsK[65536];  // buf p at p*32768: Khi 16K + Klo 16K
  __shared__ float sm[128], sl[128], srs[128];
  __shared__ float pmax[2][128], psum[2][128];

  const int bid = blockIdx.x;
  const int b = bid & 7, qt = bid >> 3;  // batch <-> XCD (K/V L2 locality)
  const int i0 = qt * 128;
  const int tid = threadIdx.x;
  const int lane = tid & 63, w = tid >> 6;  // w 0..15
  const int g = w >> 3, w8 = w & 7;         // group, wave-in-group
  const int li = lane & 15, gq = lane >> 4;
  const int mt_qk = w8 >> 1, jh = w8 & 1;  // QK: wave = (i-tile, j-half)
  const int wc = w8 * 64;                  // PV: wave owns c-strip [wc, wc+64)

  if (tid < 128) { sm[tid] = -3.0e38f; sl[tid] = 0.0f; }

  const u16* Kh = khi + (size_t)b * 4096 * 512;
  const u16* Kl = klo + (size_t)b * 4096 * 512;
  const u16* qbh =
      qhi + ((size_t)(b * 4096 + i0 + g * 64 + mt_qk * 16 + li)) * 512 + gq * 8;
  const u16* qbl =
      qlo + ((size_t)(b * 4096 + i0 + g * 64 + mt_qk * 16 + li)) * 512 + gq * 8;
  const u16* Vb = vbuf + (size_t)b * 512 * 4096;  // [c][p]
  u16* Pl = (u16*)(ldsK + 32768 + g * 16384);     // per-group P region (buf1)

  // prologue: stage (j0=0, chunk0) into buf0
  stage_tile<128, 8, 1024>(Kh, 512, ldsK, tid);
  stage_tile<128, 8, 1024>(Kl, 512, ldsK + 16384, tid);

  f32x4 Oa[4][4] = {};  // [i-tile][c-tile]

  for (int j0 = 0; j0 < 4096; j0 += 128) {
    f32x4 lg[4] = {};  // [nt]: logit[j = jh*64+nt*16+gq*4+r][i]
    // ------------- QK^T: 8 chunks of 64 c, 2-phase double-buffered -----------
#pragma unroll
    for (int cc = 0; cc < 8; cc++) {
      const int c0 = cc * 64;
      const char* cur = ldsK + (size_t)(cc & 1) * 32768;
      __syncthreads();  // stage(cc) arrived (drain) + wave sync
      if (cc < 7) {     // prefetch chunk cc+1 into the other buffer
        char* nxt = ldsK + (size_t)((cc + 1) & 1) * 32768;
        stage_tile<128, 8, 1024>(Kh + (size_t)j0 * 512 + c0 + 64, 512, nxt, tid);
        stage_tile<128, 8, 1024>(Kl + (size_t)j0 * 512 + c0 + 64, 512, nxt + 16384, tid);
      }
#pragma unroll
      for (int kk = 0; kk < 2; kk++) {
        // q hi/lo for this kk only (8 transient VGPRs; L2-hot)
        bf16x8 qhf = *reinterpret_cast<const bf16x8*>(qbh + c0 + kk * 32);
        bf16x8 qlf = *reinterpret_cast<const bf16x8*>(qbl + c0 + kk * 32);
        __builtin_amdgcn_s_setprio(1);
#pragma unroll
        for (int nt = 0; nt < 4; nt++) {
          int krow = jh * 64 + nt * 16 + li;
          bf16x8 bh = fragk<8, 7>(cur, krow, kk * 4 + gq);
          bf16x8 bl = fragk<8, 7>(cur + 16384, krow, kk * 4 + gq);
          lg[nt] = mfma16(bh, qhf, lg[nt]);  // swapped: K = A-op, Q = B-op
          lg[nt] = mfma16(bl, qhf, lg[nt]);
          lg[nt] = mfma16(bh, qlf, lg[nt]);
        }
        __builtin_amdgcn_s_setprio(0);
      }
    }
    // ---- issue V loads for jj=0,1 (hide under softmax) ----
    bf16x8 vA[4], vB[4];
#pragma unroll
    for (int t = 0; t < 4; t++)
      vA[t] = *reinterpret_cast<const bf16x8*>(
          Vb + (size_t)(wc + t * 16 + li) * 4096 + j0 + gq * 8);
#pragma unroll
    for (int t = 0; t < 4; t++)
      vB[t] = *reinterpret_cast<const bf16x8*>(
          Vb + (size_t)(wc + t * 16 + li) * 4096 + j0 + 32 + gq * 8);
    // ---------------- online softmax (row = g*64 + mt_qk*16 + li) ------------
    const int il = mt_qk * 16 + li;  // row within group (0..63)
    const int i_ = g * 64 + il;      // global row (0..127)
    {
      float mx = lg[0][0];
#pragma unroll
      for (int nt = 0; nt < 4; nt++)
#pragma unroll
        for (int r = 0; r < 4; r++) mx = fmaxf(mx, lg[nt][r]);
      mx = fmaxf(mx, __shfl_xor(mx, 16));
      mx = fmaxf(mx, __shfl_xor(mx, 32));
      if (lane < 16) pmax[jh][i_] = mx;
    }
    __syncthreads();  // B1: pmax visible; all QK LDS reads done (P region free)
    if (tid < 128) {
      float tm = fmaxf(pmax[0][tid], pmax[1][tid]);
      float mo = sm[tid];
      float mn = fmaxf(mo, tm);
      float rs = exp2f(S2C * (mo - mn));
      sm[tid] = mn; srs[tid] = rs; sl[tid] *= rs;
    }
    __syncthreads();  // B2
    {
      float mn = sm[i_];
      float ps = 0.0f;
#pragma unroll
      for (int nt = 0; nt < 4; nt++) {
        float p0 = exp2f(S2C * (lg[nt][0] - mn));
        float p1 = exp2f(S2C * (lg[nt][1] - mn));
        float p2 = exp2f(S2C * (lg[nt][2] - mn));
        float p3 = exp2f(S2C * (lg[nt][3] - mn));
        ps += (p0 + p1) + (p2 + p3);
        u16x4 pk = {f2bf(p0), f2bf(p1), f2bf(p2), f2bf(p3)};
        int jb = jh * 64 + nt * 16 + gq * 4;
        char* dst = (char*)Pl + (size_t)il * 256 +
                    (((jb >> 3) ^ (il & 15)) << 4) + ((jb << 1) & 15);
        *reinterpret_cast<u16x4*>(dst) = pk;
      }
      ps += __shfl_xor(ps, 16);
      ps += __shfl_xor(ps, 32);
      if (lane < 16) psum[jh][i_] = ps;
    }
    __syncthreads();  // B3: P + psum visible
    if (tid < 128) sl[tid] += psum[0][tid] + psum[1][tid];
    // ---- next-j0 chunk0 stage into buf0 (hides under rescale+PV) ----
    if (j0 + 128 < 4096) {  // buf0 dead (last read at cc=6); P lives in buf1
      stage_tile<128, 8, 1024>(Kh + (size_t)(j0 + 128) * 512, 512, ldsK, tid);
      stage_tile<128, 8, 1024>(Kl + (size_t)(j0 + 128) * 512, 512, ldsK + 16384, tid);
    }
    // ---- rescale O ----
#pragma unroll
    for (int mt = 0; mt < 4; mt++)
#pragma unroll
      for (int r = 0; r < 4; r++) {
        float rr = srs[g * 64 + mt * 16 + gq * 4 + r];
#pragma unroll
        for (int nt = 0; nt < 4; nt++) Oa[mt][nt][r] *= rr;
      }
    // ---------------- PV: O += P * V^T (V 2-deep reg rotation) --------------
#define PVSTEP(JJ, VREG)                                                      \
    {                                                                         \
      __builtin_amdgcn_s_setprio(1);                                          \
      _Pragma("unroll")                                                       \
      for (int mt = 0; mt < 4; mt++) {                                        \
        bf16x8 pa = fragk<16, 15>((const char*)Pl, mt * 16 + li, (JJ) * 4 + gq); \
        _Pragma("unroll")                                                     \
        for (int nt = 0; nt < 4; nt++)                                        \
          Oa[mt][nt] = mfma16(pa, VREG[nt], Oa[mt][nt]);                      \
      }                                                                       \
      __builtin_amdgcn_s_setprio(0);                                          \
    }
    PVSTEP(0, vA)
#pragma unroll
    for (int t = 0; t < 4; t++)  // vA <- jj=2 (covered by PV step 1)
      vA[t] = *reinterpret_cast<const bf16x8*>(
          Vb + (size_t)(wc + t * 16 + li) * 4096 + j0 + 64 + gq * 8);
    PVSTEP(1, vB)
#pragma unroll
    for (int t = 0; t < 4; t++)  // vB <- jj=3 (covered by PV step 2)
      vB[t] = *reinterpret_cast<const bf16x8*>(
          Vb + (size_t)(wc + t * 16 + li) * 4096 + j0 + 96 + gq * 8);
    PVSTEP(2, vA)
    PVSTEP(3, vB)
#undef PVSTEP
  }

  __syncthreads();
#pragma unroll
  for (int mt = 0; mt < 4; mt++)
#pragma unroll
    for (int r = 0; r < 4; r++) {
      int il2 = mt * 16 + gq * 4 + r;          // row within group
      float inv = 1.0f / sl[g * 64 + il2];
#pragma unroll
      for (int nt = 0; nt < 4; nt++) {
        float o = Oa[mt][nt][r] * inv;
        oout[((size_t)(b * 4096 + i0 + g * 64 + il2)) * 512 + wc + nt * 16 + li] =
            f2bf(o);
      }
    }
}

// ============================ launch ========================================
extern "C" void kernel_launch(void* const* d_in, const int* in_sizes, int n_in,
                              void* d_out, int out_size, void* d_ws, size_t ws_size,
                              hipStream_t stream) {
  const float* x = (const float*)d_in[0];
  const float* gamma = (const float*)d_in[1];
  const float* beta = (const float*)d_in[2];
  const float* wq = (const float*)d_in[3];
  const float* bq = (const float*)d_in[4];
  const float* wk = (const float*)d_in[5];
  const float* bk = (const float*)d_in[6];
  const float* wv = (const float*)d_in[7];
  const float* bv = (const float*)d_in[8];
  const float* wo = (const float*)d_in[9];
  const float* bo = (const float*)d_in[10];

  char* ws = (char*)d_ws;
  const size_t SZ = (size_t)8 * 4096 * 512 * 2;  // bytes per bf16 tensor
  const size_t NEED = 7 * SZ + 6 * (size_t)524288 + 2048;
  if (ws_size < NEED) return;

  u16* hhi = (u16*)(ws);
  u16* hlo = (u16*)(ws + SZ);
  u16* qhi = (u16*)(ws + 2 * SZ);
  u16* qlo = (u16*)(ws + 3 * SZ);
  u16* khi = (u16*)(ws + 4 * SZ);
  u16* klo = (u16*)(ws + 5 * SZ);
  u16* vbf = (u16*)(ws + 6 * SZ);
  u16* ah  = qhi;  // alias (each flash block reads its q-rows before writing its o-rows)
  u16* wqh = (u16*)(ws + 7 * SZ);
  u16* wql = wqh + 262144;
  u16* wkh = wql + 262144;
  u16* wkl = wkh + 262144;
  u16* wvb = wkl + 262144;
  u16* wob = wvb + 262144;
  float* smean = (float*)(wob + 262144);
  float* srstd = smean + 256;

  prep_w<<<1024, 256, 0, stream>>>(wq, wk, wv, wo, wqh, wql, wkh, wkl, wvb, wob);
  gn_stats<<<256, 256, 0, stream>>>(x, smean, srstd);
  gn_apply<<<dim3(4, 32, 8), 256, 0, stream>>>(x, gamma, beta, smean, srstd, hhi, hlo);
  conv_gemm<0><<<dim3(4, 32, 8), 256, 0, stream>>>(hhi, hlo, wqh, wql, bq, nullptr,
                                                   qhi, qlo, nullptr, (long)4096 * 512, 0);
  conv_gemm<0><<<dim3(4, 32, 8), 256, 0, stream>>>(hhi, hlo, wkh, wkl, bk, nullptr,
                                                   khi, klo, nullptr, (long)4096 * 512, 0);
  conv_gemm<1><<<dim3(4, 32, 8), 256, 0, stream>>>(hhi, nullptr, wvb, nullptr, bv, nullptr,
                                                   vbf, nullptr, nullptr, (long)4096 * 512, 0);
  flash_attn<<<256, 1024, 0, stream>>>(qhi, qlo, khi, klo, vbf, ah);
  conv_gemm<2><<<dim3(32, 4, 8), 256, 0, stream>>>(wob, nullptr, ah, nullptr, bo, x,
                                                   nullptr, nullptr, (float*)d_out,
                                                   0, (long)4096 * 512);
}

// Round 13
// 1365.479 us; speedup vs baseline: 1.3228x; 1.3228x over previous
//
#include <hip/hip_runtime.h>
#include <stdint.h>

typedef unsigned short u16;
typedef unsigned int u32;
typedef __attribute__((ext_vector_type(4))) float f32x4;
typedef __attribute__((ext_vector_type(8))) __bf16 bf16x8;
typedef __attribute__((ext_vector_type(4))) unsigned short u16x4;

#define DEVINL __device__ __forceinline__

// ---------- bf16 helpers (manual RTNE; storage is u16) ----------
DEVINL u16 f2bf(float f) {
  u32 u = __builtin_bit_cast(u32, f);
  u32 r = (u + 0x7fffu + ((u >> 16) & 1u)) >> 16;
  return (u16)r;
}
DEVINL float bf2f(u16 h) {
  u32 u = ((u32)h) << 16;
  return __builtin_bit_cast(float, u);
}

DEVINL f32x4 mfma16(bf16x8 a, bf16x8 b, f32x4 c) {
  return __builtin_amdgcn_mfma_f32_16x16x32_bf16(a, b, c, 0, 0, 0);
}

// ---------- async global->LDS 16B ----------
DEVINL void gload_lds16(const void* g, void* l) {
  auto gp = (__attribute__((address_space(1))) void*)(reinterpret_cast<uintptr_t>(g));
  auto lp = (__attribute__((address_space(3))) void*)(u32)(reinterpret_cast<uintptr_t>(l));
  __builtin_amdgcn_global_load_lds(gp, lp, 16, 0, 0);
}

// Stage a [ROWS][KCS*8] bf16 k-contiguous tile. LDS linear; global SOURCE slot
// inverse-XOR-swizzled so swizzled reads are conflict-free.
template <int ROWS, int KCS, int NT>
DEVINL void stage_tile(const u16* __restrict__ g, int ld, char* lds, int tid) {
  constexpr int SWZ = (KCS - 1) < 7 ? (KCS - 1) : 7;
  constexpr int CH = ROWS * KCS;  // 16B chunks
#pragma unroll
  for (int c0 = 0; c0 < CH; c0 += NT) {
    int c = c0 + tid;
    int row = c / KCS;
    int slot = c & (KCS - 1);
    const u16* src = g + (size_t)row * ld + ((slot ^ (row & SWZ)) << 3);
    char* dst = lds + (((size_t)(c0 + (tid & ~63))) << 4);  // wave-uniform base
    gload_lds16(src, dst);
  }
}

// Fragment read: 8 bf16 along k at given row. kslot in [0, KCS).
template <int KCS, int SWZM>
DEVINL bf16x8 fragk(const char* lds, int row, int kslot) {
  return *reinterpret_cast<const bf16x8*>(
      lds + (size_t)row * (KCS * 16) + (size_t)((kslot ^ (row & SWZM)) << 4));
}

// ============================ GroupNorm =====================================
__global__ __launch_bounds__(256) void gn_stats(const float* __restrict__ x,
                                                float* __restrict__ smean,
                                                float* __restrict__ srstd) {
  const int bg = blockIdx.x;
  const float4* base = reinterpret_cast<const float4*>(x + (size_t)bg * 65536);
  float s = 0.f, ss = 0.f;
  for (int i = threadIdx.x; i < 16384; i += 256) {
    float4 v = base[i];
    s += v.x + v.y + v.z + v.w;
    ss += v.x * v.x + v.y * v.y + v.z * v.z + v.w * v.w;
  }
#pragma unroll
  for (int off = 1; off < 64; off <<= 1) {
    s += __shfl_xor(s, off);
    ss += __shfl_xor(ss, off);
  }
  __shared__ float rs_[4], rss_[4];
  int w = threadIdx.x >> 6;
  if ((threadIdx.x & 63) == 0) { rs_[w] = s; rss_[w] = ss; }
  __syncthreads();
  if (threadIdx.x == 0) {
    float S = rs_[0] + rs_[1] + rs_[2] + rs_[3];
    float SS = rss_[0] + rss_[1] + rss_[2] + rss_[3];
    float mu = S * (1.0f / 65536.0f);
    float var = SS * (1.0f / 65536.0f) - mu * mu;
    smean[bg] = mu;
    srstd[bg] = 1.0f / sqrtf(var + 1e-5f);
  }
}

__global__ __launch_bounds__(256) void gn_apply(
    const float* __restrict__ x, const float* __restrict__ gamma,
    const float* __restrict__ beta, const float* __restrict__ smean,
    const float* __restrict__ srstd, u16* __restrict__ hhi, u16* __restrict__ hlo) {
  __shared__ __align__(16) u16 thi[128][136];
  __shared__ __align__(16) u16 tlo[128][136];
  const int b = blockIdx.z, p0 = blockIdx.y * 128, c0 = blockIdx.x * 128;
  const int tid = threadIdx.x;
  const int ci = tid >> 1, ph = tid & 1;
  const int c = c0 + ci;
  const int bg = b * 32 + (c >> 4);
  const float mu = smean[bg], rstd = srstd[bg];
  const float ga = gamma[c] * rstd;
  const float be = beta[c] - mu * ga;
  const float* xrow = x + ((size_t)(b * 512 + c)) * 4096 + p0;
#pragma unroll
  for (int s = 0; s < 16; s++) {
    int pj = ph * 4 + s * 8;
    float4 v = *reinterpret_cast<const float4*>(xrow + pj);
    float h0 = v.x * ga + be, h1 = v.y * ga + be, h2 = v.z * ga + be, h3 = v.w * ga + be;
    u16 a0 = f2bf(h0), a1 = f2bf(h1), a2 = f2bf(h2), a3 = f2bf(h3);
    thi[pj + 0][ci] = a0; tlo[pj + 0][ci] = f2bf(h0 - bf2f(a0));
    thi[pj + 1][ci] = a1; tlo[pj + 1][ci] = f2bf(h1 - bf2f(a1));
    thi[pj + 2][ci] = a2; tlo[pj + 2][ci] = f2bf(h2 - bf2f(a2));
    thi[pj + 3][ci] = a3; tlo[pj + 3][ci] = f2bf(h3 - bf2f(a3));
  }
  __syncthreads();
  u16* oh = hhi + ((size_t)b * 4096 + p0) * 512 + c0;
  u16* ol = hlo + ((size_t)b * 4096 + p0) * 512 + c0;
  for (int cc = tid; cc < 2048; cc += 256) {
    int p = cc >> 4, sli = cc & 15;
    *reinterpret_cast<bf16x8*>(oh + (size_t)p * 512 + sli * 8) =
        *reinterpret_cast<const bf16x8*>(&thi[p][sli * 8]);
    *reinterpret_cast<bf16x8*>(ol + (size_t)p * 512 + sli * 8) =
        *reinterpret_cast<const bf16x8*>(&tlo[p][sli * 8]);
  }
}

// ============================ weight prep ===================================
__global__ __launch_bounds__(256) void prep_w(
    const float* __restrict__ wq, const float* __restrict__ wk,
    const float* __restrict__ wv, const float* __restrict__ wo,
    u16* __restrict__ wqh, u16* __restrict__ wql, u16* __restrict__ wkh,
    u16* __restrict__ wkl, u16* __restrict__ wvb, u16* __restrict__ wob) {
  int i = blockIdx.x * 256 + threadIdx.x;
  if (i >= 262144) return;
  float a = wq[i]; u16 h = f2bf(a); wqh[i] = h; wql[i] = f2bf(a - bf2f(h));
  float bb = wk[i]; h = f2bf(bb); wkh[i] = h; wkl[i] = f2bf(bb - bf2f(h));
  wvb[i] = f2bf(wv[i]);
  wob[i] = f2bf(wo[i]);
}

// ============================ conv GEMM =====================================
template <int MODE>
__global__ __launch_bounds__(256, 2) void conv_gemm(
    const u16* __restrict__ A0, const u16* __restrict__ A1,
    const u16* __restrict__ B0, const u16* __restrict__ B1,
    const float* __restrict__ bias, const float* __restrict__ xres,
    u16* __restrict__ o0, u16* __restrict__ o1, float* __restrict__ of,
    long sAb, long sBb) {
  constexpr int LDSZ = (MODE == 0) ? 65536 : ((MODE == 1) ? 34816 : 32768);
  __shared__ __align__(16) char lds[LDSZ];
  char* ldsA = lds;
  char* ldsB = lds + 16384;

  const int b = blockIdx.z;
  const int n0 = blockIdx.x * 128;
  const int m0 = blockIdx.y * 128;
  const int tid = threadIdx.x;
  const int lane = tid & 63;
  const int w = tid >> 6;
  const int li = lane & 15, gq = lane >> 4;
  const int wm = (w >> 1) * 64, wn = (w & 1) * 64;

  const u16* Ag = A0 + (size_t)b * sAb + (size_t)m0 * 512;
  const u16* Bg = B0 + (size_t)b * sBb + (size_t)n0 * 512;
  const u16* Ag1 = (MODE == 0) ? (A1 + (size_t)b * sAb + (size_t)m0 * 512) : nullptr;
  const u16* Bg1 = (MODE == 0) ? (B1 + (size_t)b * sBb + (size_t)n0 * 512) : nullptr;

  f32x4 acc[4][4] = {};

  for (int k0 = 0; k0 < 512; k0 += 64) {
    __syncthreads();
    stage_tile<128, 8, 256>(Ag + k0, 512, ldsA, tid);
    stage_tile<128, 8, 256>(Bg + k0, 512, ldsB, tid);
    if (MODE == 0) {
      stage_tile<128, 8, 256>(Ag1 + k0, 512, lds + 32768, tid);
      stage_tile<128, 8, 256>(Bg1 + k0, 512, lds + 49152, tid);
    }
    __syncthreads();
#pragma unroll
    for (int kk = 0; kk < 2; kk++) {
      bf16x8 aF[4], bF[4], aL[4], bL[4];
#pragma unroll
      for (int t = 0; t < 4; t++) {
        aF[t] = fragk<8, 7>(ldsA, wm + t * 16 + li, kk * 4 + gq);
        bF[t] = fragk<8, 7>(ldsB, wn + t * 16 + li, kk * 4 + gq);
        if (MODE == 0) {
          aL[t] = fragk<8, 7>(lds + 32768, wm + t * 16 + li, kk * 4 + gq);
          bL[t] = fragk<8, 7>(lds + 49152, wn + t * 16 + li, kk * 4 + gq);
        }
      }
#pragma unroll
      for (int mt = 0; mt < 4; mt++)
#pragma unroll
        for (int nt = 0; nt < 4; nt++) {
          acc[mt][nt] = mfma16(aF[mt], bF[nt], acc[mt][nt]);
          if (MODE == 0) {
            acc[mt][nt] = mfma16(aF[mt], bL[nt], acc[mt][nt]);
            acc[mt][nt] = mfma16(aL[mt], bF[nt], acc[mt][nt]);
          }
        }
    }
  }

  if (MODE == 0) {
#pragma unroll
    for (int nt = 0; nt < 4; nt++) {
      int gn = n0 + wn + nt * 16 + li;
      float bs = bias[gn];
#pragma unroll
      for (int mt = 0; mt < 4; mt++)
#pragma unroll
        for (int r = 0; r < 4; r++) {
          int gm = m0 + wm + mt * 16 + gq * 4 + r;
          float v = acc[mt][nt][r] + bs;
          u16 hi = f2bf(v);
          size_t idx = ((size_t)b * 4096 + gm) * 512 + gn;
          o0[idx] = hi;
          o1[idx] = f2bf(v - bf2f(hi));
        }
    }
  } else if (MODE == 1) {
    __syncthreads();
    u16* vt = (u16*)lds;  // [128 n][136 m]
#pragma unroll
    for (int nt = 0; nt < 4; nt++) {
      int ol = wn + nt * 16 + li;
      float bs = bias[n0 + ol];
#pragma unroll
      for (int mt = 0; mt < 4; mt++)
#pragma unroll
        for (int r = 0; r < 4; r++) {
          int pl = wm + mt * 16 + gq * 4 + r;
          vt[ol * 136 + pl] = f2bf(acc[mt][nt][r] + bs);
        }
    }
    __syncthreads();
    for (int c = tid; c < 2048; c += 256) {
      int o = c >> 4, sl = c & 15;
      bf16x8 val = *reinterpret_cast<const bf16x8*>(vt + o * 136 + sl * 8);
      *reinterpret_cast<bf16x8*>(o0 + ((size_t)b * 512 + n0 + o) * 4096 + m0 + sl * 8) = val;
    }
  } else {
#pragma unroll
    for (int nt = 0; nt < 4; nt++) {
      int gn = n0 + wn + nt * 16 + li;
#pragma unroll
      for (int mt = 0; mt < 4; mt++)
#pragma unroll
        for (int r = 0; r < 4; r++) {
          int gm = m0 + wm + mt * 16 + gq * 4 + r;
          size_t idx = ((size_t)b * 512 + gm) * 4096 + gn;
          of[idx] = acc[mt][nt][r] + bias[gm] + xres[idx];
        }
    }
  }
}

// ============================ flash attention ===============================
// R8 structure with conv_gemm's barrier rhythm: K hi/lo staged in 128-c
// chunks (64KB: Khi 32K + Klo 32K), 2 buffers, 4 chunk barriers + 3 softmax
// barriers per j0 (was 11). 48 MFMA/wave per chunk barrier (2x R8). P has its
// own 16KB region (no aliasing). Next-j0 chunk0 staged after B3 (hides under
// SM+PV). All else identical to R8: swapped QK, in-lane softmax, packed 8B
// P writes, V direct global->reg 2-deep. Register peak ~70 arch + 64 AGPR ->
// no spills at the 128-VGPR cap.
#define S2C 32.64446259f  // sqrt(512)*log2(e)

__global__ __launch_bounds__(512) void flash_attn(
    const u16* __restrict__ qhi, const u16* __restrict__ qlo,
    const u16* __restrict__ khi, const u16* __restrict__ klo,
    const u16* __restrict__ vbuf, u16* __restrict__ oout) {
  __shared__ __align__(16) char ldsK[131072];  // buf p at p*65536: Khi 32K + Klo 32K
  __shared__ __align__(16) char ldsP[16384];   // P [64 i][16 slots of 16B]
  __shared__ float sm[64], sl[64], srs[64];
  __shared__ float pmax[2][64], psum[2][64];

  const int bid = blockIdx.x;
  const int b = bid & 7, qt = bid >> 3;  // batch <-> XCD (K/V L2 locality)
  const int i0 = qt * 64;
  const int tid = threadIdx.x;
  const int lane = tid & 63, w = tid >> 6;
  const int li = lane & 15, gq = lane >> 4;
  const int mt_qk = w >> 1, jh = w & 1;  // QK: wave = (i-tile, j-half)
  const int wc = w * 64;                 // PV: wave owns c-strip [wc, wc+64)

  if (tid < 64) { sm[tid] = -3.0e38f; sl[tid] = 0.0f; }

  const u16* Kh = khi + (size_t)b * 4096 * 512;
  const u16* Kl = klo + (size_t)b * 4096 * 512;
  const u16* qbh = qhi + ((size_t)(b * 4096 + i0 + mt_qk * 16 + li)) * 512 + gq * 8;
  const u16* qbl = qlo + ((size_t)(b * 4096 + i0 + mt_qk * 16 + li)) * 512 + gq * 8;
  const u16* Vb = vbuf + (size_t)b * 512 * 4096;  // [c][p]
  u16* Pl = (u16*)ldsP;

  // prologue: stage (j0=0, chunk0: c 0..127) into buf0
  stage_tile<128, 16, 512>(Kh, 512, ldsK, tid);
  stage_tile<128, 16, 512>(Kl, 512, ldsK + 32768, tid);

  f32x4 Oa[4][4] = {};  // [i-tile][c-tile]

  for (int j0 = 0; j0 < 4096; j0 += 128) {
    f32x4 lg[4] = {};  // [nt]: logit[j = jh*64+nt*16+gq*4+r][i = mt_qk*16+li]
    // ------------- QK^T: 4 chunks of 128 c, 2-phase double-buffered ----------
#pragma unroll
    for (int cc = 0; cc < 4; cc++) {
      const int c0 = cc * 128;
      const char* cur = ldsK + (size_t)(cc & 1) * 65536;
      __syncthreads();  // stage(cc) arrived (drain) + wave sync
      if (cc < 3) {     // prefetch chunk cc+1 into the other buffer
        char* nxt = ldsK + (size_t)((cc + 1) & 1) * 65536;
        stage_tile<128, 16, 512>(Kh + (size_t)j0 * 512 + c0 + 128, 512, nxt, tid);
        stage_tile<128, 16, 512>(Kl + (size_t)j0 * 512 + c0 + 128, 512, nxt + 32768, tid);
      }
#pragma unroll
      for (int kk = 0; kk < 4; kk++) {
        // q hi/lo for this kk only (8 transient VGPRs; L2-hot)
        bf16x8 qhf = *reinterpret_cast<const bf16x8*>(qbh + c0 + kk * 32);
        bf16x8 qlf = *reinterpret_cast<const bf16x8*>(qbl + c0 + kk * 32);
        __builtin_amdgcn_s_setprio(1);
#pragma unroll
        for (int nt = 0; nt < 4; nt++) {
          int krow = jh * 64 + nt * 16 + li;
          bf16x8 bh = fragk<16, 7>(cur, krow, kk * 4 + gq);
          bf16x8 bl = fragk<16, 7>(cur + 32768, krow, kk * 4 + gq);
          lg[nt] = mfma16(bh, qhf, lg[nt]);  // swapped: K = A-op, Q = B-op
          lg[nt] = mfma16(bl, qhf, lg[nt]);
          lg[nt] = mfma16(bh, qlf, lg[nt]);
        }
        __builtin_amdgcn_s_setprio(0);
      }
    }
    // ---- issue V loads for jj=0,1 (hide under softmax) ----
    bf16x8 vA[4], vB[4];
#pragma unroll
    for (int t = 0; t < 4; t++)
      vA[t] = *reinterpret_cast<const bf16x8*>(
          Vb + (size_t)(wc + t * 16 + li) * 4096 + j0 + gq * 8);
#pragma unroll
    for (int t = 0; t < 4; t++)
      vB[t] = *reinterpret_cast<const bf16x8*>(
          Vb + (size_t)(wc + t * 16 + li) * 4096 + j0 + 32 + gq * 8);
    // ---------------- online softmax (row i = mt_qk*16+li, in-lane) ----------
    const int i_ = mt_qk * 16 + li;
    {
      float mx = lg[0][0];
#pragma unroll
      for (int nt = 0; nt < 4; nt++)
#pragma unroll
        for (int r = 0; r < 4; r++) mx = fmaxf(mx, lg[nt][r]);
      mx = fmaxf(mx, __shfl_xor(mx, 16));
      mx = fmaxf(mx, __shfl_xor(mx, 32));
      if (lane < 16) pmax[jh][i_] = mx;
    }
    __syncthreads();  // B1: pmax visible; all QK LDS reads of this j0 done
    if (tid < 64) {
      float tm = fmaxf(pmax[0][tid], pmax[1][tid]);
      float mo = sm[tid];
      float mn = fmaxf(mo, tm);
      float rs = exp2f(S2C * (mo - mn));
      sm[tid] = mn; srs[tid] = rs; sl[tid] *= rs;
    }
    __syncthreads();  // B2
    {
      float mn = sm[i_];
      float ps = 0.0f;
#pragma unroll
      for (int nt = 0; nt < 4; nt++) {
        float p0 = exp2f(S2C * (lg[nt][0] - mn));
        float p1 = exp2f(S2C * (lg[nt][1] - mn));
        float p2 = exp2f(S2C * (lg[nt][2] - mn));
        float p3 = exp2f(S2C * (lg[nt][3] - mn));
        ps += (p0 + p1) + (p2 + p3);
        u16x4 pk = {f2bf(p0), f2bf(p1), f2bf(p2), f2bf(p3)};
        int jb = jh * 64 + nt * 16 + gq * 4;
        char* dst = (char*)Pl + (size_t)i_ * 256 +
                    (((jb >> 3) ^ (i_ & 15)) << 4) + ((jb << 1) & 15);
        *reinterpret_cast<u16x4*>(dst) = pk;
      }
      ps += __shfl_xor(ps, 16);
      ps += __shfl_xor(ps, 32);
      if (lane < 16) psum[jh][i_] = ps;
    }
    __syncthreads();  // B3: P + psum visible
    if (tid < 64) sl[tid] += psum[0][tid] + psum[1][tid];
    // ---- next-j0 chunk0 stage into buf0 (hides under rescale+PV) ----
    if (j0 + 128 < 4096) {  // buf0 dead (last QK read at cc=2)
      stage_tile<128, 16, 512>(Kh + (size_t)(j0 + 128) * 512, 512, ldsK, tid);
      stage_tile<128, 16, 512>(Kl + (size_t)(j0 + 128) * 512, 512, ldsK + 32768, tid);
    }
    // ---- rescale O ----
#pragma unroll
    for (int mt = 0; mt < 4; mt++)
#pragma unroll
      for (int r = 0; r < 4; r++) {
        float rr = srs[mt * 16 + gq * 4 + r];
#pragma unroll
        for (int nt = 0; nt < 4; nt++) Oa[mt][nt][r] *= rr;
      }
    // ---------------- PV: O += P * V^T (V 2-deep reg rotation) --------------
#define PVSTEP(JJ, VREG)                                                      \
    {                                                                         \
      __builtin_amdgcn_s_setprio(1);                                          \
      _Pragma("unroll")                                                       \
      for (int mt = 0; mt < 4; mt++) {                                        \
        bf16x8 pa = fragk<16, 15>((const char*)Pl, mt * 16 + li, (JJ) * 4 + gq); \
        _Pragma("unroll")                                                     \
        for (int nt = 0; nt < 4; nt++)                                        \
          Oa[mt][nt] = mfma16(pa, VREG[nt], Oa[mt][nt]);                      \
      }                                                                       \
      __builtin_amdgcn_s_setprio(0);                                          \
    }
    PVSTEP(0, vA)
#pragma unroll
    for (int t = 0; t < 4; t++)  // vA <- jj=2 (covered by PV step 1)
      vA[t] = *reinterpret_cast<const bf16x8*>(
          Vb + (size_t)(wc + t * 16 + li) * 4096 + j0 + 64 + gq * 8);
    PVSTEP(1, vB)
#pragma unroll
    for (int t = 0; t < 4; t++)  // vB <- jj=3 (covered by PV step 2)
      vB[t] = *reinterpret_cast<const bf16x8*>(
          Vb + (size_t)(wc + t * 16 + li) * 4096 + j0 + 96 + gq * 8);
    PVSTEP(2, vA)
    PVSTEP(3, vB)
#undef PVSTEP
  }

  __syncthreads();
#pragma unroll
  for (int mt = 0; mt < 4; mt++)
#pragma unroll
    for (int r = 0; r < 4; r++) {
      int i2 = mt * 16 + gq * 4 + r;
      float inv = 1.0f / sl[i2];
#pragma unroll
      for (int nt = 0; nt < 4; nt++) {
        float o = Oa[mt][nt][r] * inv;
        oout[((size_t)(b * 4096 + i0 + i2)) * 512 + wc + nt * 16 + li] = f2bf(o);
      }
    }
}

// ============================ launch ========================================
extern "C" void kernel_launch(void* const* d_in, const int* in_sizes, int n_in,
                              void* d_out, int out_size, void* d_ws, size_t ws_size,
                              hipStream_t stream) {
  const float* x = (const float*)d_in[0];
  const float* gamma = (const float*)d_in[1];
  const float* beta = (const float*)d_in[2];
  const float* wq = (const float*)d_in[3];
  const float* bq = (const float*)d_in[4];
  const float* wk = (const float*)d_in[5];
  const float* bk = (const float*)d_in[6];
  const float* wv = (const float*)d_in[7];
  const float* bv = (const float*)d_in[8];
  const float* wo = (const float*)d_in[9];
  const float* bo = (const float*)d_in[10];

  char* ws = (char*)d_ws;
  const size_t SZ = (size_t)8 * 4096 * 512 * 2;  // bytes per bf16 tensor
  const size_t NEED = 7 * SZ + 6 * (size_t)524288 + 2048;
  if (ws_size < NEED) return;

  u16* hhi = (u16*)(ws);
  u16* hlo = (u16*)(ws + SZ);
  u16* qhi = (u16*)(ws + 2 * SZ);
  u16* qlo = (u16*)(ws + 3 * SZ);
  u16* khi = (u16*)(ws + 4 * SZ);
  u16* klo = (u16*)(ws + 5 * SZ);
  u16* vbf = (u16*)(ws + 6 * SZ);
  u16* ah  = qhi;  // alias (each flash block reads its q-rows before writing its o-rows)
  u16* wqh = (u16*)(ws + 7 * SZ);
  u16* wql = wqh + 262144;
  u16* wkh = wql + 262144;
  u16* wkl = wkh + 262144;
  u16* wvb = wkl + 262144;
  u16* wob = wvb + 262144;
  float* smean = (float*)(wob + 262144);
  float* srstd = smean + 256;

  prep_w<<<1024, 256, 0, stream>>>(wq, wk, wv, wo, wqh, wql, wkh, wkl, wvb, wob);
  gn_stats<<<256, 256, 0, stream>>>(x, smean, srstd);
  gn_apply<<<dim3(4, 32, 8), 256, 0, stream>>>(x, gamma, beta, smean, srstd, hhi, hlo);
  conv_gemm<0><<<dim3(4, 32, 8), 256, 0, stream>>>(hhi, hlo, wqh, wql, bq, nullptr,
                                                   qhi, qlo, nullptr, (long)4096 * 512, 0);
  conv_gemm<0><<<dim3(4, 32, 8), 256, 0, stream>>>(hhi, hlo, wkh, wkl, bk, nullptr,
                                                   khi, klo, nullptr, (long)4096 * 512, 0);
  conv_gemm<1><<<dim3(4, 32, 8), 256, 0, stream>>>(hhi, nullptr, wvb, nullptr, bv, nullptr,
                                                   vbf, nullptr, nullptr, (long)4096 * 512, 0);
  flash_attn<<<512, 512, 0, stream>>>(qhi, qlo, khi, klo, vbf, ah);
  conv_gemm<2><<<dim3(32, 4, 8), 256, 0, stream>>>(wob, nullptr, ah, nullptr, bo, x,
                                                   nullptr, nullptr, (float*)d_out,
                                                   0, (long)4096 * 512);
}

// Round 14
// 1365.216 us; speedup vs baseline: 1.3230x; 1.0002x over previous
//
#include <hip/hip_runtime.h>
#include <stdint.h>

typedef unsigned short u16;
typedef unsigned int u32;
typedef __attribute__((ext_vector_type(4))) float f32x4;
typedef __attribute__((ext_vector_type(8))) __bf16 bf16x8;
typedef __attribute__((ext_vector_type(4))) unsigned short u16x4;

#define DEVINL __device__ __forceinline__

// ---------- bf16 helpers (manual RTNE; storage is u16) ----------
DEVINL u16 f2bf(float f) {
  u32 u = __builtin_bit_cast(u32, f);
  u32 r = (u + 0x7fffu + ((u >> 16) & 1u)) >> 16;
  return (u16)r;
}
DEVINL float bf2f(u16 h) {
  u32 u = ((u32)h) << 16;
  return __builtin_bit_cast(float, u);
}

DEVINL f32x4 mfma16(bf16x8 a, bf16x8 b, f32x4 c) {
  return __builtin_amdgcn_mfma_f32_16x16x32_bf16(a, b, c, 0, 0, 0);
}

// ---------- async global->LDS 16B ----------
DEVINL void gload_lds16(const void* g, void* l) {
  auto gp = (__attribute__((address_space(1))) void*)(reinterpret_cast<uintptr_t>(g));
  auto lp = (__attribute__((address_space(3))) void*)(u32)(reinterpret_cast<uintptr_t>(l));
  __builtin_amdgcn_global_load_lds(gp, lp, 16, 0, 0);
}

// Stage a [ROWS][KCS*8] bf16 k-contiguous tile. LDS linear; global SOURCE slot
// inverse-XOR-swizzled so swizzled reads are conflict-free.
template <int ROWS, int KCS, int NT>
DEVINL void stage_tile(const u16* __restrict__ g, int ld, char* lds, int tid) {
  constexpr int SWZ = (KCS - 1) < 7 ? (KCS - 1) : 7;
  constexpr int CH = ROWS * KCS;  // 16B chunks
#pragma unroll
  for (int c0 = 0; c0 < CH; c0 += NT) {
    int c = c0 + tid;
    int row = c / KCS;
    int slot = c & (KCS - 1);
    const u16* src = g + (size_t)row * ld + ((slot ^ (row & SWZ)) << 3);
    char* dst = lds + (((size_t)(c0 + (tid & ~63))) << 4);  // wave-uniform base
    gload_lds16(src, dst);
  }
}

// Fragment read: 8 bf16 along k at given row. kslot in [0, KCS).
template <int KCS, int SWZM>
DEVINL bf16x8 fragk(const char* lds, int row, int kslot) {
  return *reinterpret_cast<const bf16x8*>(
      lds + (size_t)row * (KCS * 16) + (size_t)((kslot ^ (row & SWZM)) << 4));
}

// ============================ GroupNorm =====================================
__global__ __launch_bounds__(256) void gn_stats(const float* __restrict__ x,
                                                float* __restrict__ smean,
                                                float* __restrict__ srstd) {
  const int bg = blockIdx.x;
  const float4* base = reinterpret_cast<const float4*>(x + (size_t)bg * 65536);
  float s = 0.f, ss = 0.f;
  for (int i = threadIdx.x; i < 16384; i += 256) {
    float4 v = base[i];
    s += v.x + v.y + v.z + v.w;
    ss += v.x * v.x + v.y * v.y + v.z * v.z + v.w * v.w;
  }
#pragma unroll
  for (int off = 1; off < 64; off <<= 1) {
    s += __shfl_xor(s, off);
    ss += __shfl_xor(ss, off);
  }
  __shared__ float rs_[4], rss_[4];
  int w = threadIdx.x >> 6;
  if ((threadIdx.x & 63) == 0) { rs_[w] = s; rss_[w] = ss; }
  __syncthreads();
  if (threadIdx.x == 0) {
    float S = rs_[0] + rs_[1] + rs_[2] + rs_[3];
    float SS = rss_[0] + rss_[1] + rss_[2] + rss_[3];
    float mu = S * (1.0f / 65536.0f);
    float var = SS * (1.0f / 65536.0f) - mu * mu;
    smean[bg] = mu;
    srstd[bg] = 1.0f / sqrtf(var + 1e-5f);
  }
}

__global__ __launch_bounds__(256) void gn_apply(
    const float* __restrict__ x, const float* __restrict__ gamma,
    const float* __restrict__ beta, const float* __restrict__ smean,
    const float* __restrict__ srstd, u16* __restrict__ hhi, u16* __restrict__ hlo) {
  __shared__ __align__(16) u16 thi[128][136];
  __shared__ __align__(16) u16 tlo[128][136];
  const int b = blockIdx.z, p0 = blockIdx.y * 128, c0 = blockIdx.x * 128;
  const int tid = threadIdx.x;
  const int ci = tid >> 1, ph = tid & 1;
  const int c = c0 + ci;
  const int bg = b * 32 + (c >> 4);
  const float mu = smean[bg], rstd = srstd[bg];
  const float ga = gamma[c] * rstd;
  const float be = beta[c] - mu * ga;
  const float* xrow = x + ((size_t)(b * 512 + c)) * 4096 + p0;
#pragma unroll
  for (int s = 0; s < 16; s++) {
    int pj = ph * 4 + s * 8;
    float4 v = *reinterpret_cast<const float4*>(xrow + pj);
    float h0 = v.x * ga + be, h1 = v.y * ga + be, h2 = v.z * ga + be, h3 = v.w * ga + be;
    u16 a0 = f2bf(h0), a1 = f2bf(h1), a2 = f2bf(h2), a3 = f2bf(h3);
    thi[pj + 0][ci] = a0; tlo[pj + 0][ci] = f2bf(h0 - bf2f(a0));
    thi[pj + 1][ci] = a1; tlo[pj + 1][ci] = f2bf(h1 - bf2f(a1));
    thi[pj + 2][ci] = a2; tlo[pj + 2][ci] = f2bf(h2 - bf2f(a2));
    thi[pj + 3][ci] = a3; tlo[pj + 3][ci] = f2bf(h3 - bf2f(a3));
  }
  __syncthreads();
  u16* oh = hhi + ((size_t)b * 4096 + p0) * 512 + c0;
  u16* ol = hlo + ((size_t)b * 4096 + p0) * 512 + c0;
  for (int cc = tid; cc < 2048; cc += 256) {
    int p = cc >> 4, sli = cc & 15;
    *reinterpret_cast<bf16x8*>(oh + (size_t)p * 512 + sli * 8) =
        *reinterpret_cast<const bf16x8*>(&thi[p][sli * 8]);
    *reinterpret_cast<bf16x8*>(ol + (size_t)p * 512 + sli * 8) =
        *reinterpret_cast<const bf16x8*>(&tlo[p][sli * 8]);
  }
}

// ============================ weight prep ===================================
__global__ __launch_bounds__(256) void prep_w(
    const float* __restrict__ wq, const float* __restrict__ wk,
    const float* __restrict__ wv, const float* __restrict__ wo,
    u16* __restrict__ wqh, u16* __restrict__ wql, u16* __restrict__ wkh,
    u16* __restrict__ wkl, u16* __restrict__ wvb, u16* __restrict__ wob) {
  int i = blockIdx.x * 256 + threadIdx.x;
  if (i >= 262144) return;
  float a = wq[i]; u16 h = f2bf(a); wqh[i] = h; wql[i] = f2bf(a - bf2f(h));
  float bb = wk[i]; h = f2bf(bb); wkh[i] = h; wkl[i] = f2bf(bb - bf2f(h));
  wvb[i] = f2bf(wv[i]);
  wob[i] = f2bf(wo[i]);
}

// ============================ conv GEMM =====================================
template <int MODE>
__global__ __launch_bounds__(256, 2) void conv_gemm(
    const u16* __restrict__ A0, const u16* __restrict__ A1,
    const u16* __restrict__ B0, const u16* __restrict__ B1,
    const float* __restrict__ bias, const float* __restrict__ xres,
    u16* __restrict__ o0, u16* __restrict__ o1, float* __restrict__ of,
    long sAb, long sBb) {
  constexpr int LDSZ = (MODE == 0) ? 65536 : ((MODE == 1) ? 34816 : 32768);
  __shared__ __align__(16) char lds[LDSZ];
  char* ldsA = lds;
  char* ldsB = lds + 16384;

  const int b = blockIdx.z;
  const int n0 = blockIdx.x * 128;
  const int m0 = blockIdx.y * 128;
  const int tid = threadIdx.x;
  const int lane = tid & 63;
  const int w = tid >> 6;
  const int li = lane & 15, gq = lane >> 4;
  const int wm = (w >> 1) * 64, wn = (w & 1) * 64;

  const u16* Ag = A0 + (size_t)b * sAb + (size_t)m0 * 512;
  const u16* Bg = B0 + (size_t)b * sBb + (size_t)n0 * 512;
  const u16* Ag1 = (MODE == 0) ? (A1 + (size_t)b * sAb + (size_t)m0 * 512) : nullptr;
  const u16* Bg1 = (MODE == 0) ? (B1 + (size_t)b * sBb + (size_t)n0 * 512) : nullptr;

  f32x4 acc[4][4] = {};

  for (int k0 = 0; k0 < 512; k0 += 64) {
    __syncthreads();
    stage_tile<128, 8, 256>(Ag + k0, 512, ldsA, tid);
    stage_tile<128, 8, 256>(Bg + k0, 512, ldsB, tid);
    if (MODE == 0) {
      stage_tile<128, 8, 256>(Ag1 + k0, 512, lds + 32768, tid);
      stage_tile<128, 8, 256>(Bg1 + k0, 512, lds + 49152, tid);
    }
    __syncthreads();
#pragma unroll
    for (int kk = 0; kk < 2; kk++) {
      bf16x8 aF[4], bF[4], aL[4], bL[4];
#pragma unroll
      for (int t = 0; t < 4; t++) {
        aF[t] = fragk<8, 7>(ldsA, wm + t * 16 + li, kk * 4 + gq);
        bF[t] = fragk<8, 7>(ldsB, wn + t * 16 + li, kk * 4 + gq);
        if (MODE == 0) {
          aL[t] = fragk<8, 7>(lds + 32768, wm + t * 16 + li, kk * 4 + gq);
          bL[t] = fragk<8, 7>(lds + 49152, wn + t * 16 + li, kk * 4 + gq);
        }
      }
#pragma unroll
      for (int mt = 0; mt < 4; mt++)
#pragma unroll
        for (int nt = 0; nt < 4; nt++) {
          acc[mt][nt] = mfma16(aF[mt], bF[nt], acc[mt][nt]);
          if (MODE == 0) {
            acc[mt][nt] = mfma16(aF[mt], bL[nt], acc[mt][nt]);
            acc[mt][nt] = mfma16(aL[mt], bF[nt], acc[mt][nt]);
          }
        }
    }
  }

  if (MODE == 0) {
#pragma unroll
    for (int nt = 0; nt < 4; nt++) {
      int gn = n0 + wn + nt * 16 + li;
      float bs = bias[gn];
#pragma unroll
      for (int mt = 0; mt < 4; mt++)
#pragma unroll
        for (int r = 0; r < 4; r++) {
          int gm = m0 + wm + mt * 16 + gq * 4 + r;
          float v = acc[mt][nt][r] + bs;
          u16 hi = f2bf(v);
          size_t idx = ((size_t)b * 4096 + gm) * 512 + gn;
          o0[idx] = hi;
          o1[idx] = f2bf(v - bf2f(hi));
        }
    }
  } else if (MODE == 1) {
    __syncthreads();
    u16* vt = (u16*)lds;  // [128 n][136 m]
#pragma unroll
    for (int nt = 0; nt < 4; nt++) {
      int ol = wn + nt * 16 + li;
      float bs = bias[n0 + ol];
#pragma unroll
      for (int mt = 0; mt < 4; mt++)
#pragma unroll
        for (int r = 0; r < 4; r++) {
          int pl = wm + mt * 16 + gq * 4 + r;
          vt[ol * 136 + pl] = f2bf(acc[mt][nt][r] + bs);
        }
    }
    __syncthreads();
    for (int c = tid; c < 2048; c += 256) {
      int o = c >> 4, sl = c & 15;
      bf16x8 val = *reinterpret_cast<const bf16x8*>(vt + o * 136 + sl * 8);
      *reinterpret_cast<bf16x8*>(o0 + ((size_t)b * 512 + n0 + o) * 4096 + m0 + sl * 8) = val;
    }
  } else {
#pragma unroll
    for (int nt = 0; nt < 4; nt++) {
      int gn = n0 + wn + nt * 16 + li;
#pragma unroll
      for (int mt = 0; mt < 4; mt++)
#pragma unroll
        for (int r = 0; r < 4; r++) {
          int gm = m0 + wm + mt * 16 + gq * 4 + r;
          size_t idx = ((size_t)b * 512 + gm) * 4096 + gn;
          of[idx] = acc[mt][nt][r] + bias[gm] + xres[idx];
        }
    }
  }
}

// ============================ flash attention ===============================
// R8 structure with conv_gemm's barrier rhythm: K hi/lo staged in 128-c
// chunks (64KB: Khi 32K + Klo 32K), 2 buffers, 4 chunk barriers + 3 softmax
// barriers per j0 (was 11). 48 MFMA/wave per chunk barrier (2x R8). P has its
// own 16KB region (no aliasing). Next-j0 chunk0 staged after B3 (hides under
// SM+PV). All else identical to R8: swapped QK, in-lane softmax, packed 8B
// P writes, V direct global->reg 2-deep. Register peak ~70 arch + 64 AGPR ->
// no spills at the 128-VGPR cap.
#define S2C 32.64446259f  // sqrt(512)*log2(e)

__global__ __launch_bounds__(512) void flash_attn(
    const u16* __restrict__ qhi, const u16* __restrict__ qlo,
    const u16* __restrict__ khi, const u16* __restrict__ klo,
    const u16* __restrict__ vbuf, u16* __restrict__ oout) {
  __shared__ __align__(16) char ldsK[131072];  // buf p at p*65536: Khi 32K + Klo 32K
  __shared__ __align__(16) char ldsP[16384];   // P [64 i][16 slots of 16B]
  __shared__ float sm[64], sl[64], srs[64];
  __shared__ float pmax[2][64], psum[2][64];

  const int bid = blockIdx.x;
  const int b = bid & 7, qt = bid >> 3;  // batch <-> XCD (K/V L2 locality)
  const int i0 = qt * 64;
  const int tid = threadIdx.x;
  const int lane = tid & 63, w = tid >> 6;
  const int li = lane & 15, gq = lane >> 4;
  const int mt_qk = w >> 1, jh = w & 1;  // QK: wave = (i-tile, j-half)
  const int wc = w * 64;                 // PV: wave owns c-strip [wc, wc+64)

  if (tid < 64) { sm[tid] = -3.0e38f; sl[tid] = 0.0f; }

  const u16* Kh = khi + (size_t)b * 4096 * 512;
  const u16* Kl = klo + (size_t)b * 4096 * 512;
  const u16* qbh = qhi + ((size_t)(b * 4096 + i0 + mt_qk * 16 + li)) * 512 + gq * 8;
  const u16* qbl = qlo + ((size_t)(b * 4096 + i0 + mt_qk * 16 + li)) * 512 + gq * 8;
  const u16* Vb = vbuf + (size_t)b * 512 * 4096;  // [c][p]
  u16* Pl = (u16*)ldsP;

  // prologue: stage (j0=0, chunk0: c 0..127) into buf0
  stage_tile<128, 16, 512>(Kh, 512, ldsK, tid);
  stage_tile<128, 16, 512>(Kl, 512, ldsK + 32768, tid);

  f32x4 Oa[4][4] = {};  // [i-tile][c-tile]

  for (int j0 = 0; j0 < 4096; j0 += 128) {
    f32x4 lg[4] = {};  // [nt]: logit[j = jh*64+nt*16+gq*4+r][i = mt_qk*16+li]
    // ------------- QK^T: 4 chunks of 128 c, 2-phase double-buffered ----------
#pragma unroll
    for (int cc = 0; cc < 4; cc++) {
      const int c0 = cc * 128;
      const char* cur = ldsK + (size_t)(cc & 1) * 65536;
      __syncthreads();  // stage(cc) arrived (drain) + wave sync
      if (cc < 3) {     // prefetch chunk cc+1 into the other buffer
        char* nxt = ldsK + (size_t)((cc + 1) & 1) * 65536;
        stage_tile<128, 16, 512>(Kh + (size_t)j0 * 512 + c0 + 128, 512, nxt, tid);
        stage_tile<128, 16, 512>(Kl + (size_t)j0 * 512 + c0 + 128, 512, nxt + 32768, tid);
      }
#pragma unroll
      for (int kk = 0; kk < 4; kk++) {
        // q hi/lo for this kk only (8 transient VGPRs; L2-hot)
        bf16x8 qhf = *reinterpret_cast<const bf16x8*>(qbh + c0 + kk * 32);
        bf16x8 qlf = *reinterpret_cast<const bf16x8*>(qbl + c0 + kk * 32);
        __builtin_amdgcn_s_setprio(1);
#pragma unroll
        for (int nt = 0; nt < 4; nt++) {
          int krow = jh * 64 + nt * 16 + li;
          bf16x8 bh = fragk<16, 7>(cur, krow, kk * 4 + gq);
          bf16x8 bl = fragk<16, 7>(cur + 32768, krow, kk * 4 + gq);
          lg[nt] = mfma16(bh, qhf, lg[nt]);  // swapped: K = A-op, Q = B-op
          lg[nt] = mfma16(bl, qhf, lg[nt]);
          lg[nt] = mfma16(bh, qlf, lg[nt]);
        }
        __builtin_amdgcn_s_setprio(0);
      }
    }
    // ---- issue V loads for jj=0,1 (hide under softmax) ----
    bf16x8 vA[4], vB[4];
#pragma unroll
    for (int t = 0; t < 4; t++)
      vA[t] = *reinterpret_cast<const bf16x8*>(
          Vb + (size_t)(wc + t * 16 + li) * 4096 + j0 + gq * 8);
#pragma unroll
    for (int t = 0; t < 4; t++)
      vB[t] = *reinterpret_cast<const bf16x8*>(
          Vb + (size_t)(wc + t * 16 + li) * 4096 + j0 + 32 + gq * 8);
    // ---------------- online softmax (row i = mt_qk*16+li, in-lane) ----------
    const int i_ = mt_qk * 16 + li;
    {
      float mx = lg[0][0];
#pragma unroll
      for (int nt = 0; nt < 4; nt++)
#pragma unroll
        for (int r = 0; r < 4; r++) mx = fmaxf(mx, lg[nt][r]);
      mx = fmaxf(mx, __shfl_xor(mx, 16));
      mx = fmaxf(mx, __shfl_xor(mx, 32));
      if (lane < 16) pmax[jh][i_] = mx;
    }
    __syncthreads();  // B1: pmax visible; all QK LDS reads of this j0 done
    if (tid < 64) {
      float tm = fmaxf(pmax[0][tid], pmax[1][tid]);
      float mo = sm[tid];
      float mn = fmaxf(mo, tm);
      float rs = exp2f(S2C * (mo - mn));
      sm[tid] = mn; srs[tid] = rs; sl[tid] *= rs;
    }
    __syncthreads();  // B2
    {
      float mn = sm[i_];
      float ps = 0.0f;
#pragma unroll
      for (int nt = 0; nt < 4; nt++) {
        float p0 = exp2f(S2C * (lg[nt][0] - mn));
        float p1 = exp2f(S2C * (lg[nt][1] - mn));
        float p2 = exp2f(S2C * (lg[nt][2] - mn));
        float p3 = exp2f(S2C * (lg[nt][3] - mn));
        ps += (p0 + p1) + (p2 + p3);
        u16x4 pk = {f2bf(p0), f2bf(p1), f2bf(p2), f2bf(p3)};
        int jb = jh * 64 + nt * 16 + gq * 4;
        char* dst = (char*)Pl + (size_t)i_ * 256 +
                    (((jb >> 3) ^ (i_ & 15)) << 4) + ((jb << 1) & 15);
        *reinterpret_cast<u16x4*>(dst) = pk;
      }
      ps += __shfl_xor(ps, 16);
      ps += __shfl_xor(ps, 32);
      if (lane < 16) psum[jh][i_] = ps;
    }
    __syncthreads();  // B3: P + psum visible
    if (tid < 64) sl[tid] += psum[0][tid] + psum[1][tid];
    // ---- next-j0 chunk0 stage into buf0 (hides under rescale+PV) ----
    if (j0 + 128 < 4096) {  // buf0 dead (last QK read at cc=2)
      stage_tile<128, 16, 512>(Kh + (size_t)(j0 + 128) * 512, 512, ldsK, tid);
      stage_tile<128, 16, 512>(Kl + (size_t)(j0 + 128) * 512, 512, ldsK + 32768, tid);
    }
    // ---- rescale O ----
#pragma unroll
    for (int mt = 0; mt < 4; mt++)
#pragma unroll
      for (int r = 0; r < 4; r++) {
        float rr = srs[mt * 16 + gq * 4 + r];
#pragma unroll
        for (int nt = 0; nt < 4; nt++) Oa[mt][nt][r] *= rr;
      }
    // ---------------- PV: O += P * V^T (V 2-deep reg rotation) --------------
#define PVSTEP(JJ, VREG)                                                      \
    {                                                                         \
      __builtin_amdgcn_s_setprio(1);                                          \
      _Pragma("unroll")                                                       \
      for (int mt = 0; mt < 4; mt++) {                                        \
        bf16x8 pa = fragk<16, 15>((const char*)Pl, mt * 16 + li, (JJ) * 4 + gq); \
        _Pragma("unroll")                                                     \
        for (int nt = 0; nt < 4; nt++)                                        \
          Oa[mt][nt] = mfma16(pa, VREG[nt], Oa[mt][nt]);                      \
      }                                                                       \
      __builtin_amdgcn_s_setprio(0);                                          \
    }
    PVSTEP(0, vA)
#pragma unroll
    for (int t = 0; t < 4; t++)  // vA <- jj=2 (covered by PV step 1)
      vA[t] = *reinterpret_cast<const bf16x8*>(
          Vb + (size_t)(wc + t * 16 + li) * 4096 + j0 + 64 + gq * 8);
    PVSTEP(1, vB)
#pragma unroll
    for (int t = 0; t < 4; t++)  // vB <- jj=3 (covered by PV step 2)
      vB[t] = *reinterpret_cast<const bf16x8*>(
          Vb + (size_t)(wc + t * 16 + li) * 4096 + j0 + 96 + gq * 8);
    PVSTEP(2, vA)
    PVSTEP(3, vB)
#undef PVSTEP
  }

  __syncthreads();
#pragma unroll
  for (int mt = 0; mt < 4; mt++)
#pragma unroll
    for (int r = 0; r < 4; r++) {
      int i2 = mt * 16 + gq * 4 + r;
      float inv = 1.0f / sl[i2];
#pragma unroll
      for (int nt = 0; nt < 4; nt++) {
        float o = Oa[mt][nt][r] * inv;
        oout[((size_t)(b * 4096 + i0 + i2)) * 512 + wc + nt * 16 + li] = f2bf(o);
      }
    }
}

// ============================ launch ========================================
extern "C" void kernel_launch(void* const* d_in, const int* in_sizes, int n_in,
                              void* d_out, int out_size, void* d_ws, size_t ws_size,
                              hipStream_t stream) {
  const float* x = (const float*)d_in[0];
  const float* gamma = (const float*)d_in[1];
  const float* beta = (const float*)d_in[2];
  const float* wq = (const float*)d_in[3];
  const float* bq = (const float*)d_in[4];
  const float* wk = (const float*)d_in[5];
  const float* bk = (const float*)d_in[6];
  const float* wv = (const float*)d_in[7];
  const float* bv = (const float*)d_in[8];
  const float* wo = (const float*)d_in[9];
  const float* bo = (const float*)d_in[10];

  char* ws = (char*)d_ws;
  const size_t SZ = (size_t)8 * 4096 * 512 * 2;  // bytes per bf16 tensor
  const size_t NEED = 7 * SZ + 6 * (size_t)524288 + 2048;
  if (ws_size < NEED) return;

  u16* hhi = (u16*)(ws);
  u16* hlo = (u16*)(ws + SZ);
  u16* qhi = (u16*)(ws + 2 * SZ);
  u16* qlo = (u16*)(ws + 3 * SZ);
  u16* khi = (u16*)(ws + 4 * SZ);
  u16* klo = (u16*)(ws + 5 * SZ);
  u16* vbf = (u16*)(ws + 6 * SZ);
  u16* ah  = qhi;  // alias (each flash block reads its q-rows before writing its o-rows)
  u16* wqh = (u16*)(ws + 7 * SZ);
  u16* wql = wqh + 262144;
  u16* wkh = wql + 262144;
  u16* wkl = wkh + 262144;
  u16* wvb = wkl + 262144;
  u16* wob = wvb + 262144;
  float* smean = (float*)(wob + 262144);
  float* srstd = smean + 256;

  prep_w<<<1024, 256, 0, stream>>>(wq, wk, wv, wo, wqh, wql, wkh, wkl, wvb, wob);
  gn_stats<<<256, 256, 0, stream>>>(x, smean, srstd);
  gn_apply<<<dim3(4, 32, 8), 256, 0, stream>>>(x, gamma, beta, smean, srstd, hhi, hlo);
  conv_gemm<0><<<dim3(4, 32, 8), 256, 0, stream>>>(hhi, hlo, wqh, wql, bq, nullptr,
                                                   qhi, qlo, nullptr, (long)4096 * 512, 0);
  conv_gemm<0><<<dim3(4, 32, 8), 256, 0, stream>>>(hhi, hlo, wkh, wkl, bk, nullptr,
                                                   khi, klo, nullptr, (long)4096 * 512, 0);
  conv_gemm<1><<<dim3(4, 32, 8), 256, 0, stream>>>(hhi, nullptr, wvb, nullptr, bv, nullptr,
                                                   vbf, nullptr, nullptr, (long)4096 * 512, 0);
  flash_attn<<<512, 512, 0, stream>>>(qhi, qlo, khi, klo, vbf, ah);
  conv_gemm<2><<<dim3(32, 4, 8), 256, 0, stream>>>(wob, nullptr, ah, nullptr, bo, x,
                                                   nullptr, nullptr, (float*)d_out,
                                                   0, (long)4096 * 512);
}

// Round 15
// 1226.437 us; speedup vs baseline: 1.4727x; 1.1132x over previous
//
#include <hip/hip_runtime.h>
#include <stdint.h>

typedef unsigned short u16;
typedef unsigned int u32;
typedef __attribute__((ext_vector_type(4))) float f32x4;
typedef __attribute__((ext_vector_type(8))) __bf16 bf16x8;
typedef __attribute__((ext_vector_type(4))) unsigned short u16x4;

#define DEVINL __device__ __forceinline__

// ---------- bf16 helpers (manual RTNE; storage is u16) ----------
DEVINL u16 f2bf(float f) {
  u32 u = __builtin_bit_cast(u32, f);
  u32 r = (u + 0x7fffu + ((u >> 16) & 1u)) >> 16;
  return (u16)r;
}
DEVINL float bf2f(u16 h) {
  u32 u = ((u32)h) << 16;
  return __builtin_bit_cast(float, u);
}

DEVINL f32x4 mfma16(bf16x8 a, bf16x8 b, f32x4 c) {
  return __builtin_amdgcn_mfma_f32_16x16x32_bf16(a, b, c, 0, 0, 0);
}

// ---------- async global->LDS 16B ----------
DEVINL void gload_lds16(const void* g, void* l) {
  auto gp = (__attribute__((address_space(1))) void*)(reinterpret_cast<uintptr_t>(g));
  auto lp = (__attribute__((address_space(3))) void*)(u32)(reinterpret_cast<uintptr_t>(l));
  __builtin_amdgcn_global_load_lds(gp, lp, 16, 0, 0);
}

// Stage a [ROWS][KCS*8] bf16 k-contiguous tile. LDS linear; global SOURCE slot
// inverse-XOR-swizzled so swizzled reads are conflict-free.
template <int ROWS, int KCS, int NT>
DEVINL void stage_tile(const u16* __restrict__ g, int ld, char* lds, int tid) {
  constexpr int SWZ = (KCS - 1) < 7 ? (KCS - 1) : 7;
  constexpr int CH = ROWS * KCS;  // 16B chunks
#pragma unroll
  for (int c0 = 0; c0 < CH; c0 += NT) {
    int c = c0 + tid;
    int row = c / KCS;
    int slot = c & (KCS - 1);
    const u16* src = g + (size_t)row * ld + ((slot ^ (row & SWZ)) << 3);
    char* dst = lds + (((size_t)(c0 + (tid & ~63))) << 4);  // wave-uniform base
    gload_lds16(src, dst);
  }
}

// Fragment read: 8 bf16 along k at given row. kslot in [0, KCS).
template <int KCS, int SWZM>
DEVINL bf16x8 fragk(const char* lds, int row, int kslot) {
  return *reinterpret_cast<const bf16x8*>(
      lds + (size_t)row * (KCS * 16) + (size_t)((kslot ^ (row & SWZM)) << 4));
}

// ============================ GroupNorm =====================================
__global__ __launch_bounds__(256) void gn_stats(const float* __restrict__ x,
                                                float* __restrict__ smean,
                                                float* __restrict__ srstd) {
  const int bg = blockIdx.x;
  const float4* base = reinterpret_cast<const float4*>(x + (size_t)bg * 65536);
  float s = 0.f, ss = 0.f;
  for (int i = threadIdx.x; i < 16384; i += 256) {
    float4 v = base[i];
    s += v.x + v.y + v.z + v.w;
    ss += v.x * v.x + v.y * v.y + v.z * v.z + v.w * v.w;
  }
#pragma unroll
  for (int off = 1; off < 64; off <<= 1) {
    s += __shfl_xor(s, off);
    ss += __shfl_xor(ss, off);
  }
  __shared__ float rs_[4], rss_[4];
  int w = threadIdx.x >> 6;
  if ((threadIdx.x & 63) == 0) { rs_[w] = s; rss_[w] = ss; }
  __syncthreads();
  if (threadIdx.x == 0) {
    float S = rs_[0] + rs_[1] + rs_[2] + rs_[3];
    float SS = rss_[0] + rss_[1] + rss_[2] + rss_[3];
    float mu = S * (1.0f / 65536.0f);
    float var = SS * (1.0f / 65536.0f) - mu * mu;
    smean[bg] = mu;
    srstd[bg] = 1.0f / sqrtf(var + 1e-5f);
  }
}

__global__ __launch_bounds__(256) void gn_apply(
    const float* __restrict__ x, const float* __restrict__ gamma,
    const float* __restrict__ beta, const float* __restrict__ smean,
    const float* __restrict__ srstd, u16* __restrict__ hhi, u16* __restrict__ hlo) {
  __shared__ __align__(16) u16 thi[128][136];
  __shared__ __align__(16) u16 tlo[128][136];
  const int b = blockIdx.z, p0 = blockIdx.y * 128, c0 = blockIdx.x * 128;
  const int tid = threadIdx.x;
  const int ci = tid >> 1, ph = tid & 1;
  const int c = c0 + ci;
  const int bg = b * 32 + (c >> 4);
  const float mu = smean[bg], rstd = srstd[bg];
  const float ga = gamma[c] * rstd;
  const float be = beta[c] - mu * ga;
  const float* xrow = x + ((size_t)(b * 512 + c)) * 4096 + p0;
#pragma unroll
  for (int s = 0; s < 16; s++) {
    int pj = ph * 4 + s * 8;
    float4 v = *reinterpret_cast<const float4*>(xrow + pj);
    float h0 = v.x * ga + be, h1 = v.y * ga + be, h2 = v.z * ga + be, h3 = v.w * ga + be;
    u16 a0 = f2bf(h0), a1 = f2bf(h1), a2 = f2bf(h2), a3 = f2bf(h3);
    thi[pj + 0][ci] = a0; tlo[pj + 0][ci] = f2bf(h0 - bf2f(a0));
    thi[pj + 1][ci] = a1; tlo[pj + 1][ci] = f2bf(h1 - bf2f(a1));
    thi[pj + 2][ci] = a2; tlo[pj + 2][ci] = f2bf(h2 - bf2f(a2));
    thi[pj + 3][ci] = a3; tlo[pj + 3][ci] = f2bf(h3 - bf2f(a3));
  }
  __syncthreads();
  u16* oh = hhi + ((size_t)b * 4096 + p0) * 512 + c0;
  u16* ol = hlo + ((size_t)b * 4096 + p0) * 512 + c0;
  for (int cc = tid; cc < 2048; cc += 256) {
    int p = cc >> 4, sli = cc & 15;
    *reinterpret_cast<bf16x8*>(oh + (size_t)p * 512 + sli * 8) =
        *reinterpret_cast<const bf16x8*>(&thi[p][sli * 8]);
    *reinterpret_cast<bf16x8*>(ol + (size_t)p * 512 + sli * 8) =
        *reinterpret_cast<const bf16x8*>(&tlo[p][sli * 8]);
  }
}

// ============================ weight prep ===================================
__global__ __launch_bounds__(256) void prep_w(
    const float* __restrict__ wq, const float* __restrict__ wk,
    const float* __restrict__ wv, const float* __restrict__ wo,
    u16* __restrict__ wqh, u16* __restrict__ wql, u16* __restrict__ wkh,
    u16* __restrict__ wkl, u16* __restrict__ wvb, u16* __restrict__ wob) {
  int i = blockIdx.x * 256 + threadIdx.x;
  if (i >= 262144) return;
  float a = wq[i]; u16 h = f2bf(a); wqh[i] = h; wql[i] = f2bf(a - bf2f(h));
  float bb = wk[i]; h = f2bf(bb); wkh[i] = h; wkl[i] = f2bf(bb - bf2f(h));
  wvb[i] = f2bf(wv[i]);
  wob[i] = f2bf(wo[i]);
}

// ============================ conv GEMM =====================================
template <int MODE>
__global__ __launch_bounds__(256, 2) void conv_gemm(
    const u16* __restrict__ A0, const u16* __restrict__ A1,
    const u16* __restrict__ B0, const u16* __restrict__ B1,
    const float* __restrict__ bias, const float* __restrict__ xres,
    u16* __restrict__ o0, u16* __restrict__ o1, float* __restrict__ of,
    long sAb, long sBb) {
  constexpr int LDSZ = (MODE == 0) ? 65536 : ((MODE == 1) ? 34816 : 32768);
  __shared__ __align__(16) char lds[LDSZ];
  char* ldsA = lds;
  char* ldsB = lds + 16384;

  const int b = blockIdx.z;
  const int n0 = blockIdx.x * 128;
  const int m0 = blockIdx.y * 128;
  const int tid = threadIdx.x;
  const int lane = tid & 63;
  const int w = tid >> 6;
  const int li = lane & 15, gq = lane >> 4;
  const int wm = (w >> 1) * 64, wn = (w & 1) * 64;

  const u16* Ag = A0 + (size_t)b * sAb + (size_t)m0 * 512;
  const u16* Bg = B0 + (size_t)b * sBb + (size_t)n0 * 512;
  const u16* Ag1 = (MODE == 0) ? (A1 + (size_t)b * sAb + (size_t)m0 * 512) : nullptr;
  const u16* Bg1 = (MODE == 0) ? (B1 + (size_t)b * sBb + (size_t)n0 * 512) : nullptr;

  f32x4 acc[4][4] = {};

  for (int k0 = 0; k0 < 512; k0 += 64) {
    __syncthreads();
    stage_tile<128, 8, 256>(Ag + k0, 512, ldsA, tid);
    stage_tile<128, 8, 256>(Bg + k0, 512, ldsB, tid);
    if (MODE == 0) {
      stage_tile<128, 8, 256>(Ag1 + k0, 512, lds + 32768, tid);
      stage_tile<128, 8, 256>(Bg1 + k0, 512, lds + 49152, tid);
    }
    __syncthreads();
#pragma unroll
    for (int kk = 0; kk < 2; kk++) {
      bf16x8 aF[4], bF[4], aL[4], bL[4];
#pragma unroll
      for (int t = 0; t < 4; t++) {
        aF[t] = fragk<8, 7>(ldsA, wm + t * 16 + li, kk * 4 + gq);
        bF[t] = fragk<8, 7>(ldsB, wn + t * 16 + li, kk * 4 + gq);
        if (MODE == 0) {
          aL[t] = fragk<8, 7>(lds + 32768, wm + t * 16 + li, kk * 4 + gq);
          bL[t] = fragk<8, 7>(lds + 49152, wn + t * 16 + li, kk * 4 + gq);
        }
      }
#pragma unroll
      for (int mt = 0; mt < 4; mt++)
#pragma unroll
        for (int nt = 0; nt < 4; nt++) {
          acc[mt][nt] = mfma16(aF[mt], bF[nt], acc[mt][nt]);
          if (MODE == 0) {
            acc[mt][nt] = mfma16(aF[mt], bL[nt], acc[mt][nt]);
            acc[mt][nt] = mfma16(aL[mt], bF[nt], acc[mt][nt]);
          }
        }
    }
  }

  if (MODE == 0) {
#pragma unroll
    for (int nt = 0; nt < 4; nt++) {
      int gn = n0 + wn + nt * 16 + li;
      float bs = bias[gn];
#pragma unroll
      for (int mt = 0; mt < 4; mt++)
#pragma unroll
        for (int r = 0; r < 4; r++) {
          int gm = m0 + wm + mt * 16 + gq * 4 + r;
          float v = acc[mt][nt][r] + bs;
          u16 hi = f2bf(v);
          size_t idx = ((size_t)b * 4096 + gm) * 512 + gn;
          o0[idx] = hi;
          o1[idx] = f2bf(v - bf2f(hi));
        }
    }
  } else if (MODE == 1) {
    __syncthreads();
    u16* vt = (u16*)lds;  // [128 n][136 m]
#pragma unroll
    for (int nt = 0; nt < 4; nt++) {
      int ol = wn + nt * 16 + li;
      float bs = bias[n0 + ol];
#pragma unroll
      for (int mt = 0; mt < 4; mt++)
#pragma unroll
        for (int r = 0; r < 4; r++) {
          int pl = wm + mt * 16 + gq * 4 + r;
          vt[ol * 136 + pl] = f2bf(acc[mt][nt][r] + bs);
        }
    }
    __syncthreads();
    for (int c = tid; c < 2048; c += 256) {
      int o = c >> 4, sl = c & 15;
      bf16x8 val = *reinterpret_cast<const bf16x8*>(vt + o * 136 + sl * 8);
      *reinterpret_cast<bf16x8*>(o0 + ((size_t)b * 512 + n0 + o) * 4096 + m0 + sl * 8) = val;
    }
  } else {
#pragma unroll
    for (int nt = 0; nt < 4; nt++) {
      int gn = n0 + wn + nt * 16 + li;
#pragma unroll
      for (int mt = 0; mt < 4; mt++)
#pragma unroll
        for (int r = 0; r < 4; r++) {
          int gm = m0 + wm + mt * 16 + gq * 4 + r;
          size_t idx = ((size_t)b * 512 + gm) * 4096 + gn;
          of[idx] = acc[mt][nt][r] + bias[gm] + xres[idx];
        }
    }
  }
}

// ============================ flash attention ===============================
// R8 geometry (proven low-conflict: [128 j][64 c] KCS=8 chunks, swapped QK,
// packed P writes, V 2-deep reg rotation) with softmax cadence TK=256:
// two j-subtiles (lg[2][4]) per softmax round -> barriers per 128 j drop
// 11 -> 9 and softmax/rescale VALU per j halves. Softmax uses 2 barriers via
// redundant-compute: after B1 every thread computes mn locally from pmax+sm;
// (jh==0,lane<16) threads write srs before B3 and sm/sl after B3 (ordering
// guaranteed by the inter-round chunk barriers). P = two 16KB tiles with the
// exact R8 write/read pattern. Chunk prefetch chains continuously across
// rounds (next-round chunk0 issued at the last chunk barrier).
#define S2C 32.64446259f  // sqrt(512)*log2(e)

__global__ __launch_bounds__(512) void flash_attn(
    const u16* __restrict__ qhi, const u16* __restrict__ qlo,
    const u16* __restrict__ khi, const u16* __restrict__ klo,
    const u16* __restrict__ vbuf, u16* __restrict__ oout) {
  __shared__ __align__(16) char ldsK[65536];  // buf p at p*32768: Khi 16K + Klo 16K
  __shared__ __align__(16) char ldsP[32768];  // P tiles: js*16384, [64 i][16 slots]
  __shared__ float sm[64], sl[64], srs[64];
  __shared__ float pmax[2][64], psum[2][64];

  const int bid = blockIdx.x;
  const int b = bid & 7, qt = bid >> 3;  // batch <-> XCD (K/V L2 locality)
  const int i0 = qt * 64;
  const int tid = threadIdx.x;
  const int lane = tid & 63, w = tid >> 6;
  const int li = lane & 15, gq = lane >> 4;
  const int mt_qk = w >> 1, jh = w & 1;  // QK: wave = (i-tile, j-half)
  const int wc = w * 64;                 // PV: wave owns c-strip [wc, wc+64)

  if (tid < 64) { sm[tid] = -3.0e38f; sl[tid] = 0.0f; }

  const u16* Kh = khi + (size_t)b * 4096 * 512;
  const u16* Kl = klo + (size_t)b * 4096 * 512;
  const u16* qbh = qhi + ((size_t)(b * 4096 + i0 + mt_qk * 16 + li)) * 512 + gq * 8;
  const u16* qbl = qlo + ((size_t)(b * 4096 + i0 + mt_qk * 16 + li)) * 512 + gq * 8;
  const u16* Vb = vbuf + (size_t)b * 512 * 4096;  // [c][p]

  // prologue: stage (round 0, js=0, chunk0) into buf0
  stage_tile<128, 8, 512>(Kh, 512, ldsK, tid);
  stage_tile<128, 8, 512>(Kl, 512, ldsK + 16384, tid);

  f32x4 Oa[4][4] = {};  // [i-tile][c-tile]

  for (int j0 = 0; j0 < 4096; j0 += 256) {
    f32x4 lg0[4] = {}, lg1[4] = {};  // per j-subtile: [nt] over wave's 64 j
    // ------ QK^T: 2 j-subtiles x 8 chunks of 64 c, 2-phase double-buffered ---
#pragma unroll
    for (int js = 0; js < 2; js++) {
      const size_t jrow = (size_t)(j0 + js * 128) * 512;
#pragma unroll
      for (int cc = 0; cc < 8; cc++) {
        const int c0 = cc * 64;
        const int n = js * 8 + cc;  // global chunk index within round (0..15)
        const char* cur = ldsK + (size_t)(n & 1) * 32768;
        __syncthreads();  // stage(n) arrived (drain) + wave sync
        {                 // prefetch chunk n+1 (n==15 -> next round js0 cc0)
          const int np = n + 1;
          const int pj = j0 + (np >> 3) * 128;  // np=16 -> j0+256
          if (pj < 4096) {
            char* nxt = ldsK + (size_t)(np & 1) * 32768;
            stage_tile<128, 8, 512>(Kh + (size_t)pj * 512 + (np & 7) * 64, 512, nxt, tid);
            stage_tile<128, 8, 512>(Kl + (size_t)pj * 512 + (np & 7) * 64, 512,
                                    nxt + 16384, tid);
          }
        }
#pragma unroll
        for (int kk = 0; kk < 2; kk++) {
          // q hi/lo for this kk only (8 transient VGPRs; L2-hot)
          bf16x8 qhf = *reinterpret_cast<const bf16x8*>(qbh + c0 + kk * 32);
          bf16x8 qlf = *reinterpret_cast<const bf16x8*>(qbl + c0 + kk * 32);
          __builtin_amdgcn_s_setprio(1);
#pragma unroll
          for (int nt = 0; nt < 4; nt++) {
            int krow = jh * 64 + nt * 16 + li;
            bf16x8 bh = fragk<8, 7>(cur, krow, kk * 4 + gq);
            bf16x8 bl = fragk<8, 7>(cur + 16384, krow, kk * 4 + gq);
            f32x4 acc = js ? lg1[nt] : lg0[nt];
            acc = mfma16(bh, qhf, acc);  // swapped: K = A-op, Q = B-op
            acc = mfma16(bl, qhf, acc);
            acc = mfma16(bh, qlf, acc);
            if (js) lg1[nt] = acc; else lg0[nt] = acc;
          }
          __builtin_amdgcn_s_setprio(0);
        }
      }
    }
    // ---- issue V loads for jj=0,1 (hide under softmax) ----
    bf16x8 vA[4], vB[4];
#pragma unroll
    for (int t = 0; t < 4; t++)
      vA[t] = *reinterpret_cast<const bf16x8*>(
          Vb + (size_t)(wc + t * 16 + li) * 4096 + j0 + gq * 8);
#pragma unroll
    for (int t = 0; t < 4; t++)
      vB[t] = *reinterpret_cast<const bf16x8*>(
          Vb + (size_t)(wc + t * 16 + li) * 4096 + j0 + 32 + gq * 8);
    // ---------------- online softmax over 256 j (2 barriers) -----------------
    const int i_ = mt_qk * 16 + li;
    {
      float mx = lg0[0][0];
#pragma unroll
      for (int nt = 0; nt < 4; nt++)
#pragma unroll
        for (int r = 0; r < 4; r++) {
          mx = fmaxf(mx, lg0[nt][r]);
          mx = fmaxf(mx, lg1[nt][r]);
        }
      mx = fmaxf(mx, __shfl_xor(mx, 16));
      mx = fmaxf(mx, __shfl_xor(mx, 32));
      if (lane < 16) pmax[jh][i_] = mx;
    }
    __syncthreads();  // B1: pmax visible; all QK LDS reads of this round done
    const float mo = sm[i_];  // sm not yet updated this round (write is post-B3)
    const float mn = fmaxf(mo, fmaxf(pmax[0][i_], pmax[1][i_]));
    if (jh == 0 && lane < 16) srs[i_] = exp2f(S2C * (mo - mn));  // read post-B3 only
    {
      float ps = 0.0f;
#pragma unroll
      for (int js = 0; js < 2; js++) {
        char* Pt = ldsP + (size_t)js * 16384;
#pragma unroll
        for (int nt = 0; nt < 4; nt++) {
          f32x4 lgv = js ? lg1[nt] : lg0[nt];
          float p0 = exp2f(S2C * (lgv[0] - mn));
          float p1 = exp2f(S2C * (lgv[1] - mn));
          float p2 = exp2f(S2C * (lgv[2] - mn));
          float p3 = exp2f(S2C * (lgv[3] - mn));
          ps += (p0 + p1) + (p2 + p3);
          u16x4 pk = {f2bf(p0), f2bf(p1), f2bf(p2), f2bf(p3)};
          int jb = jh * 64 + nt * 16 + gq * 4;
          char* dst = Pt + (size_t)i_ * 256 +
                      (((jb >> 3) ^ (i_ & 15)) << 4) + ((jb << 1) & 15);
          *reinterpret_cast<u16x4*>(dst) = pk;
        }
      }
      ps += __shfl_xor(ps, 16);
      ps += __shfl_xor(ps, 32);
      if (lane < 16) psum[jh][i_] = ps;
    }
    __syncthreads();  // B3: P tiles + psum + srs visible
    if (jh == 0 && lane < 16) {
      sl[i_] = sl[i_] * srs[i_] + psum[0][i_] + psum[1][i_];
      sm[i_] = mn;  // safe: next read of sm is after next round's B1
    }
    // ---- rescale O (once per 256 j) ----
#pragma unroll
    for (int mt = 0; mt < 4; mt++)
#pragma unroll
      for (int r = 0; r < 4; r++) {
        float rr = srs[mt * 16 + gq * 4 + r];
#pragma unroll
        for (int nt = 0; nt < 4; nt++) Oa[mt][nt][r] *= rr;
      }
    // -------- PV: O += P * V^T, 8 steps (V 2-deep reg rotation) --------------
#define PVSTEP(JJ, VREG)                                                      \
    {                                                                         \
      const char* Pt = ldsP + (size_t)((JJ) >> 2) * 16384;                    \
      __builtin_amdgcn_s_setprio(1);                                          \
      _Pragma("unroll")                                                       \
      for (int mt = 0; mt < 4; mt++) {                                        \
        bf16x8 pa = fragk<16, 15>(Pt, mt * 16 + li, ((JJ) & 3) * 4 + gq);     \
        _Pragma("unroll")                                                     \
        for (int nt = 0; nt < 4; nt++)                                        \
          Oa[mt][nt] = mfma16(pa, VREG[nt], Oa[mt][nt]);                      \
      }                                                                       \
      __builtin_amdgcn_s_setprio(0);                                          \
    }
#define VLOAD(VREG, OFF)                                                      \
    _Pragma("unroll")                                                         \
    for (int t = 0; t < 4; t++)                                               \
      VREG[t] = *reinterpret_cast<const bf16x8*>(                             \
          Vb + (size_t)(wc + t * 16 + li) * 4096 + j0 + (OFF) + gq * 8);
    PVSTEP(0, vA) VLOAD(vA, 64)
    PVSTEP(1, vB) VLOAD(vB, 96)
    PVSTEP(2, vA) VLOAD(vA, 128)
    PVSTEP(3, vB) VLOAD(vB, 160)
    PVSTEP(4, vA) VLOAD(vA, 192)
    PVSTEP(5, vB) VLOAD(vB, 224)
    PVSTEP(6, vA)
    PVSTEP(7, vB)
#undef PVSTEP
#undef VLOAD
  }

  __syncthreads();
#pragma unroll
  for (int mt = 0; mt < 4; mt++)
#pragma unroll
    for (int r = 0; r < 4; r++) {
      int i2 = mt * 16 + gq * 4 + r;
      float inv = 1.0f / sl[i2];
#pragma unroll
      for (int nt = 0; nt < 4; nt++) {
        float o = Oa[mt][nt][r] * inv;
        oout[((size_t)(b * 4096 + i0 + i2)) * 512 + wc + nt * 16 + li] = f2bf(o);
      }
    }
}

// ============================ launch ========================================
extern "C" void kernel_launch(void* const* d_in, const int* in_sizes, int n_in,
                              void* d_out, int out_size, void* d_ws, size_t ws_size,
                              hipStream_t stream) {
  const float* x = (const float*)d_in[0];
  const float* gamma = (const float*)d_in[1];
  const float* beta = (const float*)d_in[2];
  const float* wq = (const float*)d_in[3];
  const float* bq = (const float*)d_in[4];
  const float* wk = (const float*)d_in[5];
  const float* bk = (const float*)d_in[6];
  const float* wv = (const float*)d_in[7];
  const float* bv = (const float*)d_in[8];
  const float* wo = (const float*)d_in[9];
  const float* bo = (const float*)d_in[10];

  char* ws = (char*)d_ws;
  const size_t SZ = (size_t)8 * 4096 * 512 * 2;  // bytes per bf16 tensor
  const size_t NEED = 7 * SZ + 6 * (size_t)524288 + 2048;
  if (ws_size < NEED) return;

  u16* hhi = (u16*)(ws);
  u16* hlo = (u16*)(ws + SZ);
  u16* qhi = (u16*)(ws + 2 * SZ);
  u16* qlo = (u16*)(ws + 3 * SZ);
  u16* khi = (u16*)(ws + 4 * SZ);
  u16* klo = (u16*)(ws + 5 * SZ);
  u16* vbf = (u16*)(ws + 6 * SZ);
  u16* ah  = qhi;  // alias (each flash block reads its q-rows before writing its o-rows)
  u16* wqh = (u16*)(ws + 7 * SZ);
  u16* wql = wqh + 262144;
  u16* wkh = wql + 262144;
  u16* wkl = wkh + 262144;
  u16* wvb = wkl + 262144;
  u16* wob = wvb + 262144;
  float* smean = (float*)(wob + 262144);
  float* srstd = smean + 256;

  prep_w<<<1024, 256, 0, stream>>>(wq, wk, wv, wo, wqh, wql, wkh, wkl, wvb, wob);
  gn_stats<<<256, 256, 0, stream>>>(x, smean, srstd);
  gn_apply<<<dim3(4, 32, 8), 256, 0, stream>>>(x, gamma, beta, smean, srstd, hhi, hlo);
  conv_gemm<0><<<dim3(4, 32, 8), 256, 0, stream>>>(hhi, hlo, wqh, wql, bq, nullptr,
                                                   qhi, qlo, nullptr, (long)4096 * 512, 0);
  conv_gemm<0><<<dim3(4, 32, 8), 256, 0, stream>>>(hhi, hlo, wkh, wkl, bk, nullptr,
                                                   khi, klo, nullptr, (long)4096 * 512, 0);
  conv_gemm<1><<<dim3(4, 32, 8), 256, 0, stream>>>(hhi, nullptr, wvb, nullptr, bv, nullptr,
                                                   vbf, nullptr, nullptr, (long)4096 * 512, 0);
  flash_attn<<<512, 512, 0, stream>>>(qhi, qlo, khi, klo, vbf, ah);
  conv_gemm<2><<<dim3(32, 4, 8), 256, 0, stream>>>(wob, nullptr, ah, nullptr, bo, x,
                                                   nullptr, nullptr, (float*)d_out,
                                                   0, (long)4096 * 512);
}

// Round 16
// 1030.499 us; speedup vs baseline: 1.7528x; 1.1901x over previous
//
#include <hip/hip_runtime.h>
#include <stdint.h>

typedef unsigned short u16;
typedef unsigned int u32;
typedef __attribute__((ext_vector_type(4))) float f32x4;
typedef __attribute__((ext_vector_type(8))) __bf16 bf16x8;
typedef __attribute__((ext_vector_type(4))) unsigned short u16x4;

#define DEVINL __device__ __forceinline__

// ---------- bf16 helpers (manual RTNE; storage is u16) ----------
DEVINL u16 f2bf(float f) {
  u32 u = __builtin_bit_cast(u32, f);
  u32 r = (u + 0x7fffu + ((u >> 16) & 1u)) >> 16;
  return (u16)r;
}
DEVINL float bf2f(u16 h) {
  u32 u = ((u32)h) << 16;
  return __builtin_bit_cast(float, u);
}

DEVINL f32x4 mfma16(bf16x8 a, bf16x8 b, f32x4 c) {
  return __builtin_amdgcn_mfma_f32_16x16x32_bf16(a, b, c, 0, 0, 0);
}

// ---------- async global->LDS 16B ----------
DEVINL void gload_lds16(const void* g, void* l) {
  auto gp = (__attribute__((address_space(1))) void*)(reinterpret_cast<uintptr_t>(g));
  auto lp = (__attribute__((address_space(3))) void*)(u32)(reinterpret_cast<uintptr_t>(l));
  __builtin_amdgcn_global_load_lds(gp, lp, 16, 0, 0);
}

// Stage a [ROWS][KCS*8] bf16 k-contiguous tile. LDS linear; global SOURCE slot
// inverse-XOR-swizzled so swizzled reads are conflict-free.
template <int ROWS, int KCS, int NT>
DEVINL void stage_tile(const u16* __restrict__ g, int ld, char* lds, int tid) {
  constexpr int SWZ = (KCS - 1) < 7 ? (KCS - 1) : 7;
  constexpr int CH = ROWS * KCS;  // 16B chunks
#pragma unroll
  for (int c0 = 0; c0 < CH; c0 += NT) {
    int c = c0 + tid;
    int row = c / KCS;
    int slot = c & (KCS - 1);
    const u16* src = g + (size_t)row * ld + ((slot ^ (row & SWZ)) << 3);
    char* dst = lds + (((size_t)(c0 + (tid & ~63))) << 4);  // wave-uniform base
    gload_lds16(src, dst);
  }
}

// Fragment read: 8 bf16 along k at given row. kslot in [0, KCS).
template <int KCS, int SWZM>
DEVINL bf16x8 fragk(const char* lds, int row, int kslot) {
  return *reinterpret_cast<const bf16x8*>(
      lds + (size_t)row * (KCS * 16) + (size_t)((kslot ^ (row & SWZM)) << 4));
}

// ============================ GroupNorm =====================================
__global__ __launch_bounds__(256) void gn_stats(const float* __restrict__ x,
                                                float* __restrict__ smean,
                                                float* __restrict__ srstd) {
  const int bg = blockIdx.x;
  const float4* base = reinterpret_cast<const float4*>(x + (size_t)bg * 65536);
  float s = 0.f, ss = 0.f;
  for (int i = threadIdx.x; i < 16384; i += 256) {
    float4 v = base[i];
    s += v.x + v.y + v.z + v.w;
    ss += v.x * v.x + v.y * v.y + v.z * v.z + v.w * v.w;
  }
#pragma unroll
  for (int off = 1; off < 64; off <<= 1) {
    s += __shfl_xor(s, off);
    ss += __shfl_xor(ss, off);
  }
  __shared__ float rs_[4], rss_[4];
  int w = threadIdx.x >> 6;
  if ((threadIdx.x & 63) == 0) { rs_[w] = s; rss_[w] = ss; }
  __syncthreads();
  if (threadIdx.x == 0) {
    float S = rs_[0] + rs_[1] + rs_[2] + rs_[3];
    float SS = rss_[0] + rss_[1] + rss_[2] + rss_[3];
    float mu = S * (1.0f / 65536.0f);
    float var = SS * (1.0f / 65536.0f) - mu * mu;
    smean[bg] = mu;
    srstd[bg] = 1.0f / sqrtf(var + 1e-5f);
  }
}

__global__ __launch_bounds__(256) void gn_apply(
    const float* __restrict__ x, const float* __restrict__ gamma,
    const float* __restrict__ beta, const float* __restrict__ smean,
    const float* __restrict__ srstd, u16* __restrict__ hhi, u16* __restrict__ hlo) {
  __shared__ __align__(16) u16 thi[128][136];
  __shared__ __align__(16) u16 tlo[128][136];
  const int b = blockIdx.z, p0 = blockIdx.y * 128, c0 = blockIdx.x * 128;
  const int tid = threadIdx.x;
  const int ci = tid >> 1, ph = tid & 1;
  const int c = c0 + ci;
  const int bg = b * 32 + (c >> 4);
  const float mu = smean[bg], rstd = srstd[bg];
  const float ga = gamma[c] * rstd;
  const float be = beta[c] - mu * ga;
  const float* xrow = x + ((size_t)(b * 512 + c)) * 4096 + p0;
#pragma unroll
  for (int s = 0; s < 16; s++) {
    int pj = ph * 4 + s * 8;
    float4 v = *reinterpret_cast<const float4*>(xrow + pj);
    float h0 = v.x * ga + be, h1 = v.y * ga + be, h2 = v.z * ga + be, h3 = v.w * ga + be;
    u16 a0 = f2bf(h0), a1 = f2bf(h1), a2 = f2bf(h2), a3 = f2bf(h3);
    thi[pj + 0][ci] = a0; tlo[pj + 0][ci] = f2bf(h0 - bf2f(a0));
    thi[pj + 1][ci] = a1; tlo[pj + 1][ci] = f2bf(h1 - bf2f(a1));
    thi[pj + 2][ci] = a2; tlo[pj + 2][ci] = f2bf(h2 - bf2f(a2));
    thi[pj + 3][ci] = a3; tlo[pj + 3][ci] = f2bf(h3 - bf2f(a3));
  }
  __syncthreads();
  u16* oh = hhi + ((size_t)b * 4096 + p0) * 512 + c0;
  u16* ol = hlo + ((size_t)b * 4096 + p0) * 512 + c0;
  for (int cc = tid; cc < 2048; cc += 256) {
    int p = cc >> 4, sli = cc & 15;
    *reinterpret_cast<bf16x8*>(oh + (size_t)p * 512 + sli * 8) =
        *reinterpret_cast<const bf16x8*>(&thi[p][sli * 8]);
    *reinterpret_cast<bf16x8*>(ol + (size_t)p * 512 + sli * 8) =
        *reinterpret_cast<const bf16x8*>(&tlo[p][sli * 8]);
  }
}

// ============================ weight prep ===================================
__global__ __launch_bounds__(256) void prep_w(
    const float* __restrict__ wq, const float* __restrict__ wk,
    const float* __restrict__ wv, const float* __restrict__ wo,
    u16* __restrict__ wqh, u16* __restrict__ wql, u16* __restrict__ wkh,
    u16* __restrict__ wkl, u16* __restrict__ wvb, u16* __restrict__ wob) {
  int i = blockIdx.x * 256 + threadIdx.x;
  if (i >= 262144) return;
  float a = wq[i]; u16 h = f2bf(a); wqh[i] = h; wql[i] = f2bf(a - bf2f(h));
  float bb = wk[i]; h = f2bf(bb); wkh[i] = h; wkl[i] = f2bf(bb - bf2f(h));
  wvb[i] = f2bf(wv[i]);
  wob[i] = f2bf(wo[i]);
}

// ============================ conv GEMM =====================================
template <int MODE>
__global__ __launch_bounds__(256, 2) void conv_gemm(
    const u16* __restrict__ A0, const u16* __restrict__ A1,
    const u16* __restrict__ B0, const u16* __restrict__ B1,
    const float* __restrict__ bias, const float* __restrict__ xres,
    u16* __restrict__ o0, u16* __restrict__ o1, float* __restrict__ of,
    long sAb, long sBb) {
  constexpr int LDSZ = (MODE == 0) ? 65536 : ((MODE == 1) ? 34816 : 32768);
  __shared__ __align__(16) char lds[LDSZ];
  char* ldsA = lds;
  char* ldsB = lds + 16384;

  const int b = blockIdx.z;
  const int n0 = blockIdx.x * 128;
  const int m0 = blockIdx.y * 128;
  const int tid = threadIdx.x;
  const int lane = tid & 63;
  const int w = tid >> 6;
  const int li = lane & 15, gq = lane >> 4;
  const int wm = (w >> 1) * 64, wn = (w & 1) * 64;

  const u16* Ag = A0 + (size_t)b * sAb + (size_t)m0 * 512;
  const u16* Bg = B0 + (size_t)b * sBb + (size_t)n0 * 512;
  const u16* Ag1 = (MODE == 0) ? (A1 + (size_t)b * sAb + (size_t)m0 * 512) : nullptr;
  const u16* Bg1 = (MODE == 0) ? (B1 + (size_t)b * sBb + (size_t)n0 * 512) : nullptr;

  f32x4 acc[4][4] = {};

  for (int k0 = 0; k0 < 512; k0 += 64) {
    __syncthreads();
    stage_tile<128, 8, 256>(Ag + k0, 512, ldsA, tid);
    stage_tile<128, 8, 256>(Bg + k0, 512, ldsB, tid);
    if (MODE == 0) {
      stage_tile<128, 8, 256>(Ag1 + k0, 512, lds + 32768, tid);
      stage_tile<128, 8, 256>(Bg1 + k0, 512, lds + 49152, tid);
    }
    __syncthreads();
#pragma unroll
    for (int kk = 0; kk < 2; kk++) {
      bf16x8 aF[4], bF[4], aL[4], bL[4];
#pragma unroll
      for (int t = 0; t < 4; t++) {
        aF[t] = fragk<8, 7>(ldsA, wm + t * 16 + li, kk * 4 + gq);
        bF[t] = fragk<8, 7>(ldsB, wn + t * 16 + li, kk * 4 + gq);
        if (MODE == 0) {
          aL[t] = fragk<8, 7>(lds + 32768, wm + t * 16 + li, kk * 4 + gq);
          bL[t] = fragk<8, 7>(lds + 49152, wn + t * 16 + li, kk * 4 + gq);
        }
      }
#pragma unroll
      for (int mt = 0; mt < 4; mt++)
#pragma unroll
        for (int nt = 0; nt < 4; nt++) {
          acc[mt][nt] = mfma16(aF[mt], bF[nt], acc[mt][nt]);
          if (MODE == 0) {
            acc[mt][nt] = mfma16(aF[mt], bL[nt], acc[mt][nt]);
            acc[mt][nt] = mfma16(aL[mt], bF[nt], acc[mt][nt]);
          }
        }
    }
  }

  if (MODE == 0) {
#pragma unroll
    for (int nt = 0; nt < 4; nt++) {
      int gn = n0 + wn + nt * 16 + li;
      float bs = bias[gn];
#pragma unroll
      for (int mt = 0; mt < 4; mt++)
#pragma unroll
        for (int r = 0; r < 4; r++) {
          int gm = m0 + wm + mt * 16 + gq * 4 + r;
          float v = acc[mt][nt][r] + bs;
          u16 hi = f2bf(v);
          size_t idx = ((size_t)b * 4096 + gm) * 512 + gn;
          o0[idx] = hi;
          o1[idx] = f2bf(v - bf2f(hi));
        }
    }
  } else if (MODE == 1) {
    __syncthreads();
    u16* vt = (u16*)lds;  // [128 n][136 m]
#pragma unroll
    for (int nt = 0; nt < 4; nt++) {
      int ol = wn + nt * 16 + li;
      float bs = bias[n0 + ol];
#pragma unroll
      for (int mt = 0; mt < 4; mt++)
#pragma unroll
        for (int r = 0; r < 4; r++) {
          int pl = wm + mt * 16 + gq * 4 + r;
          vt[ol * 136 + pl] = f2bf(acc[mt][nt][r] + bs);
        }
    }
    __syncthreads();
    for (int c = tid; c < 2048; c += 256) {
      int o = c >> 4, sl = c & 15;
      bf16x8 val = *reinterpret_cast<const bf16x8*>(vt + o * 136 + sl * 8);
      *reinterpret_cast<bf16x8*>(o0 + ((size_t)b * 512 + n0 + o) * 4096 + m0 + sl * 8) = val;
    }
  } else {
#pragma unroll
    for (int nt = 0; nt < 4; nt++) {
      int gn = n0 + wn + nt * 16 + li;
#pragma unroll
      for (int mt = 0; mt < 4; mt++)
#pragma unroll
        for (int r = 0; r < 4; r++) {
          int gm = m0 + wm + mt * 16 + gq * 4 + r;
          size_t idx = ((size_t)b * 512 + gm) * 4096 + gn;
          of[idx] = acc[mt][nt][r] + bias[gm] + xres[idx];
        }
    }
  }
}

// ============================ flash attention ===============================
// R15 (TK=256 softmax cadence, 2-barrier softmax, R8 chunk geometry) with the
// spill fixed: V jj0/jj1 register loads moved AFTER B3 (post P-write), so the
// 32 V regs never overlap the lg0+lg1 live range. All phases fit the 128-reg
// cap: softmax ~112, PV ~100. (R15's early V loads caused 620MB scratch WRITE.)
#define S2C 32.64446259f  // sqrt(512)*log2(e)

__global__ __launch_bounds__(512) void flash_attn(
    const u16* __restrict__ qhi, const u16* __restrict__ qlo,
    const u16* __restrict__ khi, const u16* __restrict__ klo,
    const u16* __restrict__ vbuf, u16* __restrict__ oout) {
  __shared__ __align__(16) char ldsK[65536];  // buf p at p*32768: Khi 16K + Klo 16K
  __shared__ __align__(16) char ldsP[32768];  // P tiles: js*16384, [64 i][16 slots]
  __shared__ float sm[64], sl[64], srs[64];
  __shared__ float pmax[2][64], psum[2][64];

  const int bid = blockIdx.x;
  const int b = bid & 7, qt = bid >> 3;  // batch <-> XCD (K/V L2 locality)
  const int i0 = qt * 64;
  const int tid = threadIdx.x;
  const int lane = tid & 63, w = tid >> 6;
  const int li = lane & 15, gq = lane >> 4;
  const int mt_qk = w >> 1, jh = w & 1;  // QK: wave = (i-tile, j-half)
  const int wc = w * 64;                 // PV: wave owns c-strip [wc, wc+64)

  if (tid < 64) { sm[tid] = -3.0e38f; sl[tid] = 0.0f; }

  const u16* Kh = khi + (size_t)b * 4096 * 512;
  const u16* Kl = klo + (size_t)b * 4096 * 512;
  const u16* qbh = qhi + ((size_t)(b * 4096 + i0 + mt_qk * 16 + li)) * 512 + gq * 8;
  const u16* qbl = qlo + ((size_t)(b * 4096 + i0 + mt_qk * 16 + li)) * 512 + gq * 8;
  const u16* Vb = vbuf + (size_t)b * 512 * 4096;  // [c][p]

  // prologue: stage (round 0, js=0, chunk0) into buf0
  stage_tile<128, 8, 512>(Kh, 512, ldsK, tid);
  stage_tile<128, 8, 512>(Kl, 512, ldsK + 16384, tid);

  f32x4 Oa[4][4] = {};  // [i-tile][c-tile]

  for (int j0 = 0; j0 < 4096; j0 += 256) {
    f32x4 lg0[4] = {}, lg1[4] = {};  // per j-subtile: [nt] over wave's 64 j
    // ------ QK^T: 2 j-subtiles x 8 chunks of 64 c, 2-phase double-buffered ---
#pragma unroll
    for (int js = 0; js < 2; js++) {
      const size_t jrow = (size_t)(j0 + js * 128) * 512;
      (void)jrow;
#pragma unroll
      for (int cc = 0; cc < 8; cc++) {
        const int c0 = cc * 64;
        const int n = js * 8 + cc;  // global chunk index within round (0..15)
        const char* cur = ldsK + (size_t)(n & 1) * 32768;
        __syncthreads();  // stage(n) arrived (drain) + wave sync
        {                 // prefetch chunk n+1 (n==15 -> next round js0 cc0)
          const int np = n + 1;
          const int pj = j0 + (np >> 3) * 128;  // np=16 -> j0+256
          if (pj < 4096) {
            char* nxt = ldsK + (size_t)(np & 1) * 32768;
            stage_tile<128, 8, 512>(Kh + (size_t)pj * 512 + (np & 7) * 64, 512, nxt, tid);
            stage_tile<128, 8, 512>(Kl + (size_t)pj * 512 + (np & 7) * 64, 512,
                                    nxt + 16384, tid);
          }
        }
#pragma unroll
        for (int kk = 0; kk < 2; kk++) {
          // q hi/lo for this kk only (8 transient VGPRs; L2-hot)
          bf16x8 qhf = *reinterpret_cast<const bf16x8*>(qbh + c0 + kk * 32);
          bf16x8 qlf = *reinterpret_cast<const bf16x8*>(qbl + c0 + kk * 32);
          __builtin_amdgcn_s_setprio(1);
#pragma unroll
          for (int nt = 0; nt < 4; nt++) {
            int krow = jh * 64 + nt * 16 + li;
            bf16x8 bh = fragk<8, 7>(cur, krow, kk * 4 + gq);
            bf16x8 bl = fragk<8, 7>(cur + 16384, krow, kk * 4 + gq);
            f32x4 acc = js ? lg1[nt] : lg0[nt];
            acc = mfma16(bh, qhf, acc);  // swapped: K = A-op, Q = B-op
            acc = mfma16(bl, qhf, acc);
            acc = mfma16(bh, qlf, acc);
            if (js) lg1[nt] = acc; else lg0[nt] = acc;
          }
          __builtin_amdgcn_s_setprio(0);
        }
      }
    }
    // ---------------- online softmax over 256 j (2 barriers) -----------------
    const int i_ = mt_qk * 16 + li;
    {
      float mx = lg0[0][0];
#pragma unroll
      for (int nt = 0; nt < 4; nt++)
#pragma unroll
        for (int r = 0; r < 4; r++) {
          mx = fmaxf(mx, lg0[nt][r]);
          mx = fmaxf(mx, lg1[nt][r]);
        }
      mx = fmaxf(mx, __shfl_xor(mx, 16));
      mx = fmaxf(mx, __shfl_xor(mx, 32));
      if (lane < 16) pmax[jh][i_] = mx;
    }
    __syncthreads();  // B1: pmax visible; all QK LDS reads of this round done
    const float mo = sm[i_];  // sm not yet updated this round (write is post-B3)
    const float mn = fmaxf(mo, fmaxf(pmax[0][i_], pmax[1][i_]));
    if (jh == 0 && lane < 16) srs[i_] = exp2f(S2C * (mo - mn));  // read post-B3 only
    {
      float ps = 0.0f;
#pragma unroll
      for (int js = 0; js < 2; js++) {
        char* Pt = ldsP + (size_t)js * 16384;
#pragma unroll
        for (int nt = 0; nt < 4; nt++) {
          f32x4 lgv = js ? lg1[nt] : lg0[nt];
          float p0 = exp2f(S2C * (lgv[0] - mn));
          float p1 = exp2f(S2C * (lgv[1] - mn));
          float p2 = exp2f(S2C * (lgv[2] - mn));
          float p3 = exp2f(S2C * (lgv[3] - mn));
          ps += (p0 + p1) + (p2 + p3);
          u16x4 pk = {f2bf(p0), f2bf(p1), f2bf(p2), f2bf(p3)};
          int jb = jh * 64 + nt * 16 + gq * 4;
          char* dst = Pt + (size_t)i_ * 256 +
                      (((jb >> 3) ^ (i_ & 15)) << 4) + ((jb << 1) & 15);
          *reinterpret_cast<u16x4*>(dst) = pk;
        }
      }
      ps += __shfl_xor(ps, 16);
      ps += __shfl_xor(ps, 32);
      if (lane < 16) psum[jh][i_] = ps;
    }
    __syncthreads();  // B3: P tiles + psum + srs visible
    if (jh == 0 && lane < 16) {
      sl[i_] = sl[i_] * srs[i_] + psum[0][i_] + psum[1][i_];
      sm[i_] = mn;  // safe: next read of sm is after next round's B1
    }
    // ---- V loads for jj=0,1 (AFTER lg dies: no live-range overlap) ----
    bf16x8 vA[4], vB[4];
#pragma unroll
    for (int t = 0; t < 4; t++)
      vA[t] = *reinterpret_cast<const bf16x8*>(
          Vb + (size_t)(wc + t * 16 + li) * 4096 + j0 + gq * 8);
#pragma unroll
    for (int t = 0; t < 4; t++)
      vB[t] = *reinterpret_cast<const bf16x8*>(
          Vb + (size_t)(wc + t * 16 + li) * 4096 + j0 + 32 + gq * 8);
    // ---- rescale O (once per 256 j) ----
#pragma unroll
    for (int mt = 0; mt < 4; mt++)
#pragma unroll
      for (int r = 0; r < 4; r++) {
        float rr = srs[mt * 16 + gq * 4 + r];
#pragma unroll
        for (int nt = 0; nt < 4; nt++) Oa[mt][nt][r] *= rr;
      }
    // -------- PV: O += P * V^T, 8 steps (V 2-deep reg rotation) --------------
#define PVSTEP(JJ, VREG)                                                      \
    {                                                                         \
      const char* Pt = ldsP + (size_t)((JJ) >> 2) * 16384;                    \
      __builtin_amdgcn_s_setprio(1);                                          \
      _Pragma("unroll")                                                       \
      for (int mt = 0; mt < 4; mt++) {                                        \
        bf16x8 pa = fragk<16, 15>(Pt, mt * 16 + li, ((JJ) & 3) * 4 + gq);     \
        _Pragma("unroll")                                                     \
        for (int nt = 0; nt < 4; nt++)                                        \
          Oa[mt][nt] = mfma16(pa, VREG[nt], Oa[mt][nt]);                      \
      }                                                                       \
      __builtin_amdgcn_s_setprio(0);                                          \
    }
#define VLOAD(VREG, OFF)                                                      \
    _Pragma("unroll")                                                         \
    for (int t = 0; t < 4; t++)                                               \
      VREG[t] = *reinterpret_cast<const bf16x8*>(                             \
          Vb + (size_t)(wc + t * 16 + li) * 4096 + j0 + (OFF) + gq * 8);
    PVSTEP(0, vA) VLOAD(vA, 64)
    PVSTEP(1, vB) VLOAD(vB, 96)
    PVSTEP(2, vA) VLOAD(vA, 128)
    PVSTEP(3, vB) VLOAD(vB, 160)
    PVSTEP(4, vA) VLOAD(vA, 192)
    PVSTEP(5, vB) VLOAD(vB, 224)
    PVSTEP(6, vA)
    PVSTEP(7, vB)
#undef PVSTEP
#undef VLOAD
  }

  __syncthreads();
#pragma unroll
  for (int mt = 0; mt < 4; mt++)
#pragma unroll
    for (int r = 0; r < 4; r++) {
      int i2 = mt * 16 + gq * 4 + r;
      float inv = 1.0f / sl[i2];
#pragma unroll
      for (int nt = 0; nt < 4; nt++) {
        float o = Oa[mt][nt][r] * inv;
        oout[((size_t)(b * 4096 + i0 + i2)) * 512 + wc + nt * 16 + li] = f2bf(o);
      }
    }
}

// ============================ launch ========================================
extern "C" void kernel_launch(void* const* d_in, const int* in_sizes, int n_in,
                              void* d_out, int out_size, void* d_ws, size_t ws_size,
                              hipStream_t stream) {
  const float* x = (const float*)d_in[0];
  const float* gamma = (const float*)d_in[1];
  const float* beta = (const float*)d_in[2];
  const float* wq = (const float*)d_in[3];
  const float* bq = (const float*)d_in[4];
  const float* wk = (const float*)d_in[5];
  const float* bk = (const float*)d_in[6];
  const float* wv = (const float*)d_in[7];
  const float* bv = (const float*)d_in[8];
  const float* wo = (const float*)d_in[9];
  const float* bo = (const float*)d_in[10];

  char* ws = (char*)d_ws;
  const size_t SZ = (size_t)8 * 4096 * 512 * 2;  // bytes per bf16 tensor
  const size_t NEED = 7 * SZ + 6 * (size_t)524288 + 2048;
  if (ws_size < NEED) return;

  u16* hhi = (u16*)(ws);
  u16* hlo = (u16*)(ws + SZ);
  u16* qhi = (u16*)(ws + 2 * SZ);
  u16* qlo = (u16*)(ws + 3 * SZ);
  u16* khi = (u16*)(ws + 4 * SZ);
  u16* klo = (u16*)(ws + 5 * SZ);
  u16* vbf = (u16*)(ws + 6 * SZ);
  u16* ah  = qhi;  // alias (each flash block reads its q-rows before writing its o-rows)
  u16* wqh = (u16*)(ws + 7 * SZ);
  u16* wql = wqh + 262144;
  u16* wkh = wql + 262144;
  u16* wkl = wkh + 262144;
  u16* wvb = wkl + 262144;
  u16* wob = wvb + 262144;
  float* smean = (float*)(wob + 262144);
  float* srstd = smean + 256;

  prep_w<<<1024, 256, 0, stream>>>(wq, wk, wv, wo, wqh, wql, wkh, wkl, wvb, wob);
  gn_stats<<<256, 256, 0, stream>>>(x, smean, srstd);
  gn_apply<<<dim3(4, 32, 8), 256, 0, stream>>>(x, gamma, beta, smean, srstd, hhi, hlo);
  conv_gemm<0><<<dim3(4, 32, 8), 256, 0, stream>>>(hhi, hlo, wqh, wql, bq, nullptr,
                                                   qhi, qlo, nullptr, (long)4096 * 512, 0);
  conv_gemm<0><<<dim3(4, 32, 8), 256, 0, stream>>>(hhi, hlo, wkh, wkl, bk, nullptr,
                                                   khi, klo, nullptr, (long)4096 * 512, 0);
  conv_gemm<1><<<dim3(4, 32, 8), 256, 0, stream>>>(hhi, nullptr, wvb, nullptr, bv, nullptr,
                                                   vbf, nullptr, nullptr, (long)4096 * 512, 0);
  flash_attn<<<512, 512, 0, stream>>>(qhi, qlo, khi, klo, vbf, ah);
  conv_gemm<2><<<dim3(32, 4, 8), 256, 0, stream>>>(wob, nullptr, ah, nullptr, bo, x,
                                                   nullptr, nullptr, (float*)d_out,
                                                   0, (long)4096 * 512);
}